// Round 12
// baseline (499.615 us; speedup 1.0000x reference)
//
#include <hip/hip_runtime.h>

#define NEG 0.2f

typedef __attribute__((ext_vector_type(4))) float f32x4;
typedef __attribute__((ext_vector_type(8))) short bf16x8;

// ---------- bf16 pack/unpack (RNE) ----------
__device__ __forceinline__ float blo(unsigned u) { return __uint_as_float(u << 16); }
__device__ __forceinline__ float bhi(unsigned u) { return __uint_as_float(u & 0xffff0000u); }
__device__ __forceinline__ unsigned bpack(float a, float b) {
  unsigned ua = __float_as_uint(a), ub = __float_as_uint(b);
  unsigned ra = (ua + 0x7fffu + ((ua >> 16) & 1u)) >> 16;
  unsigned rb = (ub + 0x7fffu + ((ub >> 16) & 1u)) >> 16;
  return ra | (rb << 16);
}
__device__ __forceinline__ unsigned short b16(float a) {
  unsigned ua = __float_as_uint(a);
  return (unsigned short)((ua + 0x7fffu + ((ua >> 16) & 1u)) >> 16);
}

// 16-lane xor-butterfly reduce via ds_swizzle (pattern immediate, 3 inst/stage).
__device__ __forceinline__ float red16(float t) {
  t += __int_as_float(__builtin_amdgcn_ds_swizzle(__float_as_int(t), 0x041F));  // xor 1
  t += __int_as_float(__builtin_amdgcn_ds_swizzle(__float_as_int(t), 0x081F));  // xor 2
  t += __int_as_float(__builtin_amdgcn_ds_swizzle(__float_as_int(t), 0x101F));  // xor 4
  t += __int_as_float(__builtin_amdgcn_ds_swizzle(__float_as_int(t), 0x201F));  // xor 8
  return t;
}

// ---------- detect whether edge_index arrived as int64 or int32 ----------
__global__ void detect_idx64(const void* __restrict__ ei, int n_nodes, int* __restrict__ flag) {
  const long long* e64 = (const long long*)ei;
  long long v = e64[threadIdx.x];
  bool ok = (v >= 0 && v < (long long)n_nodes);
  unsigned long long b = __ballot(ok);
  if (threadIdx.x == 0) *flag = (b == ~0ull) ? 1 : 0;
}

__device__ __forceinline__ void get_edge(const void* __restrict__ ei, int is64, int e, int E,
                                         int& src, int& dst) {
  if (e >= E) { src = e - E; dst = e - E; return; }  // self-loops appended
  if (is64) {
    const long long* p = (const long long*)ei;
    src = (int)p[e];
    dst = (int)p[(size_t)E + e];
  } else {
    const int* p = (const int*)ei;
    src = p[e];
    dst = p[E + e];
  }
}

// ---------- XCD-range-partitioned CSR build ----------
__global__ void hist_xcd_k(const void* __restrict__ ei, const int* __restrict__ flag,
                           int* __restrict__ count, int E, int Etot, int rsz, int N, int ce) {
  int r = blockIdx.x & 7, c = blockIdx.x >> 3;
  int lo = r * rsz, hi = min(N, lo + rsz);
  int eend = min(Etot, (c + 1) * ce);
  int is64 = *flag;
  for (int e = c * ce + threadIdx.x; e < eend; e += 256) {
    int src, dst;
    get_edge(ei, is64, e, E, src, dst);
    (void)src;
    if (dst >= lo && dst < hi) atomicAdd(&count[dst], 1);
  }
}

__global__ void scatter_xcd_k(const void* __restrict__ ei, const int* __restrict__ flag,
                              int* __restrict__ cursor, int* __restrict__ bucket,
                              int E, int Etot, int rsz, int N, int ce) {
  int r = blockIdx.x & 7, c = blockIdx.x >> 3;
  int lo = r * rsz, hi = min(N, lo + rsz);
  int eend = min(Etot, (c + 1) * ce);
  int is64 = *flag;
  for (int e = c * ce + threadIdx.x; e < eend; e += 256) {
    int src, dst;
    get_edge(ei, is64, e, E, src, dst);
    if (dst >= lo && dst < hi) {
      int pos = atomicAdd(&cursor[dst], 1);
      bucket[pos] = src;
    }
  }
}

__global__ void scan1_k(const int* __restrict__ count, int* __restrict__ bsum, int n) {
  __shared__ int sd[256];
  int i = blockIdx.x * 256 + threadIdx.x;
  sd[threadIdx.x] = (i < n) ? count[i] : 0;
  __syncthreads();
  for (int o = 128; o; o >>= 1) {
    if (threadIdx.x < o) sd[threadIdx.x] += sd[threadIdx.x + o];
    __syncthreads();
  }
  if (threadIdx.x == 0) bsum[blockIdx.x] = sd[0];
}

__global__ void scan2_k(int* __restrict__ bsum, int nb) {
  __shared__ int sd[256];
  int v = (threadIdx.x < nb) ? bsum[threadIdx.x] : 0;
  sd[threadIdx.x] = v;
  __syncthreads();
  for (int o = 1; o < 256; o <<= 1) {
    int t = (threadIdx.x >= o) ? sd[threadIdx.x - o] : 0;
    __syncthreads();
    sd[threadIdx.x] += t;
    __syncthreads();
  }
  if (threadIdx.x < nb) bsum[threadIdx.x] = sd[threadIdx.x] - v;
}

__global__ void scan3_k(const int* __restrict__ count, const int* __restrict__ bsum,
                        int* __restrict__ off, int* __restrict__ cursor, int n, int etot) {
  __shared__ int sd[256];
  int i = blockIdx.x * 256 + threadIdx.x;
  int v = (i < n) ? count[i] : 0;
  sd[threadIdx.x] = v;
  __syncthreads();
  for (int o = 1; o < 256; o <<= 1) {
    int t = (threadIdx.x >= o) ? sd[threadIdx.x - o] : 0;
    __syncthreads();
    sd[threadIdx.x] += t;
    __syncthreads();
  }
  if (i < n) {
    int ex = bsum[blockIdx.x] + sd[threadIdx.x] - v;
    off[i] = ex;
    cursor[i] = ex;
  }
  if (i == 0) off[n] = etot;
}

// ---------- degree-equalized node permutation (counting sort by degree) ----------
__global__ void deg_hist_k(const int* __restrict__ off, int* __restrict__ dcount, int N) {
  int i = blockIdx.x * 256 + threadIdx.x;
  if (i >= N) return;
  int d = off[i + 1] - off[i];
  d = d < 511 ? d : 511;
  atomicAdd(&dcount[d], 1);
}

__global__ void deg_scan_k(const int* __restrict__ dcount, int* __restrict__ dcursor) {
  __shared__ int sd[512];   // 1 block, 512 threads
  int t = threadIdx.x;
  int v = dcount[t];
  sd[t] = v;
  __syncthreads();
  for (int o = 1; o < 512; o <<= 1) {
    int x = (t >= o) ? sd[t - o] : 0;
    __syncthreads();
    sd[t] += x;
    __syncthreads();
  }
  dcursor[t] = sd[t] - v;   // exclusive
}

__global__ void deg_scatter_k(const int* __restrict__ off, int* __restrict__ dcursor,
                              int* __restrict__ perm, int N) {
  int i = blockIdx.x * 256 + threadIdx.x;
  if (i >= N) return;
  int d = off[i + 1] - off[i];
  d = d < 511 ? d : 511;
  int pos = atomicAdd(&dcursor[d], 1);
  perm[pos] = i;
}

// ---------- pack [Wl|Wr] (fp32 row-major [128][C]) -> WbT[col][k] bf16 ----------
__global__ void packW_k(const float* __restrict__ Wl, const float* __restrict__ Wr,
                        unsigned short* __restrict__ WbT, int C, int total) {
  int i = blockIdx.x * 256 + threadIdx.x;
  if (i >= total) return;
  int col = i >> 7, k = i & 127;
  float v = (col < C) ? Wl[(size_t)k * C + col] : Wr[(size_t)k * C + (col - C)];
  WbT[i] = b16(v);
}

// ---------- MFMA dual GEMM: [xl|xr] = X(fp32) @ WbT(bf16), K=128 ----------
template <int NCOL, int C, int HS, bool PAIRI>
__global__ void mfma_dual_gemm(const float* __restrict__ X, const unsigned short* __restrict__ WbT,
                               unsigned* __restrict__ xl_p, unsigned* __restrict__ xr_p, int nrows) {
  constexpr int NF = NCOL / 16;
  constexpr int NPM = C / 2;
  constexpr int FPM = C / 16;
  constexpr int FPH = HS / 16;
  constexpr int POFF = HS / 32;
  const int wave = threadIdx.x >> 6;
  const int lane = threadIdx.x & 63;
  const int row0 = blockIdx.x * 64 + wave * 16;
  const int rA = row0 + (lane & 15);
  const int rAc = (rA < nrows) ? rA : (nrows - 1);
  const int kA = (lane >> 4) * 8;
  const int colB = lane & 15;

  f32x4 acc[NF];
#pragma unroll
  for (int f = 0; f < NF; ++f) acc[f] = (f32x4){0.f, 0.f, 0.f, 0.f};

#pragma unroll
  for (int k0 = 0; k0 < 128; k0 += 32) {
    const float* ax = &X[(size_t)rAc * 128 + k0 + kA];
    float4 a0 = *(const float4*)ax;
    float4 a1 = *(const float4*)(ax + 4);
    union { unsigned u[4]; bf16x8 v; } af;
    af.u[0] = bpack(a0.x, a0.y);
    af.u[1] = bpack(a0.z, a0.w);
    af.u[2] = bpack(a1.x, a1.y);
    af.u[3] = bpack(a1.z, a1.w);
#pragma unroll
    for (int nf = 0; nf < NF; ++nf) {
      union { uint4 u4; bf16x8 v; } bf;
      bf.u4 = *(const uint4*)&WbT[(size_t)(nf * 16 + colB) * 128 + k0 + kA];
      acc[nf] = __builtin_amdgcn_mfma_f32_16x16x32_bf16(af.v, bf.v, acc[nf], 0, 0, 0);
    }
  }

#pragma unroll
  for (int mat = 0; mat < 2; ++mat) {
    unsigned* outp = mat ? xr_p : xl_p;
#pragma unroll
    for (int mf = 0; mf < FPM; ++mf) {
      int head = mf / FPH, hf = mf % FPH;
      if (hf >= POFF) continue;
      int f = mat * FPM + mf;
      int pair = hf * 16 + colB;
      int q = PAIRI ? (2 * pair + head) : (head * (HS / 2) + pair);
#pragma unroll
      for (int r = 0; r < 4; ++r) {
        int row = row0 + ((lane >> 4) << 2) + r;
        if (row < nrows) outp[(size_t)row * NPM + q] = bpack(acc[f][r], acc[f + POFF][r]);
      }
    }
  }
}

// ---------- layer 1 fused: 16 lanes per node (4 nodes/wave), degree-sorted ----------
__global__ void fused_layer1_k(const unsigned* __restrict__ xl_p, const unsigned* __restrict__ xr_p,
                               const int* __restrict__ off, const int* __restrict__ bucket,
                               const int* __restrict__ perm,
                               const float* __restrict__ att, const float* __restrict__ b,
                               float* __restrict__ h1, int N) {
  int grp = threadIdx.x >> 4, sub = threadIdx.x & 15;
  int idx = blockIdx.x * 16 + grp;
  if (idx >= N) return;
  int node = perm[idx];
  const int c0 = 2 * sub, c1 = 2 * sub + 1;
  uint4 xr4 = *(const uint4*)&xr_p[(size_t)node * 64 + 4 * sub];
  float xr0 = blo(xr4.x), xr1 = bhi(xr4.x);   // h0: ch c0, c0+32
  float xr2 = blo(xr4.y), xr3 = bhi(xr4.y);   // h1: ch 64+c0, 96+c0
  float xr4f = blo(xr4.z), xr5 = bhi(xr4.z);  // h0: ch c1, c1+32
  float xr6 = blo(xr4.w), xr7 = bhi(xr4.w);   // h1: ch 64+c1, 96+c1
  float at0 = att[c0], at1 = att[c0 + 32], at2 = att[64 + c0], at3 = att[96 + c0];
  float at4 = att[c1], at5 = att[c1 + 32], at6 = att[64 + c1], at7 = att[96 + c1];

  float m0 = -INFINITY, m1 = -INFINITY, s0 = 0.f, s1 = 0.f;
  float o0 = 0.f, o1 = 0.f, o2 = 0.f, o3 = 0.f, o4 = 0.f, o5 = 0.f, o6 = 0.f, o7 = 0.f;
  int j = off[node], jend = off[node + 1];

  auto tpart = [&](uint4 v, float* vv, float& t0, float& t1) {
    vv[0] = blo(v.x); vv[1] = bhi(v.x); vv[2] = blo(v.y); vv[3] = bhi(v.y);
    vv[4] = blo(v.z); vv[5] = bhi(v.z); vv[6] = blo(v.w); vv[7] = bhi(v.w);
    float e0 = vv[0] + xr0;  e0 = fmaxf(e0, NEG * e0);
    float e1 = vv[1] + xr1;  e1 = fmaxf(e1, NEG * e1);
    float e2 = vv[2] + xr2;  e2 = fmaxf(e2, NEG * e2);
    float e3 = vv[3] + xr3;  e3 = fmaxf(e3, NEG * e3);
    float e4 = vv[4] + xr4f; e4 = fmaxf(e4, NEG * e4);
    float e5 = vv[5] + xr5;  e5 = fmaxf(e5, NEG * e5);
    float e6 = vv[6] + xr6;  e6 = fmaxf(e6, NEG * e6);
    float e7 = vv[7] + xr7;  e7 = fmaxf(e7, NEG * e7);
    t0 = fmaf(e0, at0, e1 * at1) + fmaf(e4, at4, e5 * at5);
    t1 = fmaf(e2, at2, e3 * at3) + fmaf(e6, at6, e7 * at7);
  };

  int b0i = bucket[j];
  int b1i = (j + 1 < jend) ? bucket[j + 1] : b0i;
  uint4 v0 = *(const uint4*)&xl_p[(size_t)b0i * 64 + 4 * sub];
  uint4 v1 = *(const uint4*)&xl_p[(size_t)b1i * 64 + 4 * sub];
  bool val1 = (j + 1 < jend);

  for (;;) {
    float va[8], vb[8], t0a, t1a, t0b, t1b;
    tpart(v0, va, t0a, t1a);
    tpart(v1, vb, t0b, t1b);
    if (!val1) { t0b = -1e30f; t1b = -1e30f; }

    int jn = j + 2;
    bool more = jn < jend;
    if (more) {
      int n0 = bucket[jn];
      int n1 = (jn + 1 < jend) ? bucket[jn + 1] : n0;
      v0 = *(const uint4*)&xl_p[(size_t)n0 * 64 + 4 * sub];
      v1 = *(const uint4*)&xl_p[(size_t)n1 * 64 + 4 * sub];
      val1 = (jn + 1 < jend);
    }

    t0a = red16(t0a); t1a = red16(t1a);
    t0b = red16(t0b); t1b = red16(t1b);

    float tm0 = fmaxf(t0a, t0b), tm1 = fmaxf(t1a, t1b);
    if (__any((tm0 > m0 + 8.f) || (tm1 > m1 + 8.f))) {
      float nm0 = fmaxf(m0, tm0), nm1 = fmaxf(m1, tm1);
      float c0r = __expf(m0 - nm0), c1r = __expf(m1 - nm1);
      s0 *= c0r; s1 *= c1r;
      o0 *= c0r; o1 *= c0r; o4 *= c0r; o5 *= c0r;
      o2 *= c1r; o3 *= c1r; o6 *= c1r; o7 *= c1r;
      m0 = nm0; m1 = nm1;
    }
    float p0a = __expf(t0a - m0), p1a = __expf(t1a - m1);
    float p0b = __expf(t0b - m0), p1b = __expf(t1b - m1);
    s0 += p0a + p0b;
    s1 += p1a + p1b;
    o0 = fmaf(p0a, va[0], fmaf(p0b, vb[0], o0));
    o1 = fmaf(p0a, va[1], fmaf(p0b, vb[1], o1));
    o4 = fmaf(p0a, va[4], fmaf(p0b, vb[4], o4));
    o5 = fmaf(p0a, va[5], fmaf(p0b, vb[5], o5));
    o2 = fmaf(p1a, va[2], fmaf(p1b, vb[2], o2));
    o3 = fmaf(p1a, va[3], fmaf(p1b, vb[3], o3));
    o6 = fmaf(p1a, va[6], fmaf(p1b, vb[6], o6));
    o7 = fmaf(p1a, va[7], fmaf(p1b, vb[7], o7));
    if (!more) break;
    j = jn;
  }

  float i0 = 1.f / s0, i1 = 1.f / s1;
  auto elu = [](float r) { return r > 0.f ? r : __expf(r) - 1.f; };
  float* row = h1 + (size_t)node * 128;
  float2 w;
  w.x = elu(fmaf(o0, i0, b[c0]));       w.y = elu(fmaf(o4, i0, b[c1]));
  *(float2*)&row[c0] = w;
  w.x = elu(fmaf(o1, i0, b[c0 + 32]));  w.y = elu(fmaf(o5, i0, b[c1 + 32]));
  *(float2*)&row[c0 + 32] = w;
  w.x = elu(fmaf(o2, i1, b[64 + c0])); w.y = elu(fmaf(o6, i1, b[64 + c1]));
  *(float2*)&row[64 + c0] = w;
  w.x = elu(fmaf(o3, i1, b[96 + c0])); w.y = elu(fmaf(o7, i1, b[96 + c1]));
  *(float2*)&row[96 + c0] = w;
}

// ---------- layer 2 fused: 16 lanes per node, degree-sorted ----------
__global__ void fused_layer2_k(const unsigned* __restrict__ xl_p, const unsigned* __restrict__ xr_p,
                               const int* __restrict__ off, const int* __restrict__ bucket,
                               const int* __restrict__ perm,
                               const float* __restrict__ att, const float* __restrict__ b,
                               float* __restrict__ out, int N) {
  int idx = blockIdx.x * 16 + (threadIdx.x >> 4);
  int lane = threadIdx.x & 15;
  if (idx >= N) return;
  int node = perm[idx];
  unsigned xru = xr_p[(size_t)node * 16 + lane];
  float xr_a = blo(xru), xr_b = bhi(xru);
  float att_a = att[lane], att_b = att[lane + 16];
  float m = -INFINITY, s = 0.f, oa = 0.f, ob = 0.f;
  int j0 = off[node], jend = off[node + 1];

  auto tpart = [&](unsigned vu, float& va, float& vb) {
    va = blo(vu); vb = bhi(vu);
    float ea = va + xr_a; ea = fmaxf(ea, NEG * ea);
    float eb = vb + xr_b; eb = fmaxf(eb, NEG * eb);
    return fmaf(ea, att_a, eb * att_b);
  };

  auto upd4 = [&](const unsigned* v, int nvalid) {
    float va0, vb0, va1, vb1, va2, vb2, va3, vb3;
    float t0 = tpart(v[0], va0, vb0);
    float t1 = tpart(v[1], va1, vb1);
    float t2 = tpart(v[2], va2, vb2);
    float t3 = tpart(v[3], va3, vb3);
    if (nvalid < 4) {
      if (nvalid <= 1) t1 = -1e30f;
      if (nvalid <= 2) t2 = -1e30f;
      t3 = -1e30f;
    }
    t0 = red16(t0); t1 = red16(t1); t2 = red16(t2); t3 = red16(t3);
    float tm = fmaxf(fmaxf(t0, t1), fmaxf(t2, t3));
    if (__any(tm > m + 8.f)) {
      float nm = fmaxf(m, tm);
      float c = __expf(m - nm);
      s *= c; oa *= c; ob *= c;
      m = nm;
    }
    float p0 = __expf(t0 - m), p1 = __expf(t1 - m);
    float p2 = __expf(t2 - m), p3 = __expf(t3 - m);
    s += (p0 + p1) + (p2 + p3);
    oa = fmaf(p0, va0, fmaf(p1, va1, fmaf(p2, va2, fmaf(p3, va3, oa))));
    ob = fmaf(p0, vb0, fmaf(p1, vb1, fmaf(p2, vb2, fmaf(p3, vb3, ob))));
  };

  unsigned cv[4], nv[4];
  int deg = jend - j0;
#pragma unroll
  for (int k = 0; k < 4; ++k) {
    int idx2 = j0 + ((k < deg) ? k : 0);
    cv[k] = xl_p[(size_t)bucket[idx2] * 16 + lane];
  }
  int j = j0;
  for (;;) {
    int jn = j + 4;
    bool more = jn < jend;
    if (more) {
      int rem = jend - jn;
#pragma unroll
      for (int k = 0; k < 4; ++k) {
        int idx2 = jn + ((k < rem) ? k : 0);
        nv[k] = xl_p[(size_t)bucket[idx2] * 16 + lane];
      }
    }
    int nvalid = jend - j; if (nvalid > 4) nvalid = 4;
    upd4(cv, nvalid);
    if (!more) break;
#pragma unroll
    for (int k = 0; k < 4; ++k) cv[k] = nv[k];
    j = jn;
  }

  float inv = 1.f / s;
  out[(size_t)node * 32 + lane]      = fmaf(oa, inv, b[lane]);
  out[(size_t)node * 32 + 16 + lane] = fmaf(ob, inv, b[lane + 16]);
}

extern "C" void kernel_launch(void* const* d_in, const int* in_sizes, int n_in,
                              void* d_out, int out_size, void* d_ws, size_t ws_size,
                              hipStream_t stream) {
  const float* x    = (const float*)d_in[0];
  const void*  ei   = d_in[1];
  const float* Wl1  = (const float*)d_in[2];
  const float* Wr1  = (const float*)d_in[3];
  const float* att1 = (const float*)d_in[4];
  const float* b1   = (const float*)d_in[5];
  const float* Wl2  = (const float*)d_in[6];
  const float* Wr2  = (const float*)d_in[7];
  const float* att2 = (const float*)d_in[8];
  const float* b2   = (const float*)d_in[9];

  const int N = in_sizes[0] / 128;
  const int E = in_sizes[1] / 2;
  const int Etot = E + N;
  float* out = (float*)d_out;
  (void)out_size; (void)n_in; (void)ws_size;

  // ---------------- workspace layout ----------------
  char* ws = (char*)d_ws;
  size_t off_b = 0;
  auto alloc = [&](size_t bytes) {
    void* p = ws + off_b;
    off_b += (bytes + 255) & ~(size_t)255;
    return p;
  };
  unsigned*       xl1p   = (unsigned*)alloc((size_t)N * 64 * 4);  // packed bf16 pairs
  unsigned*       xr1p   = (unsigned*)alloc((size_t)N * 64 * 4);
  float*          h1     = (float*)alloc((size_t)N * 128 * 4);
  int*            bucket = (int*)alloc((size_t)(Etot + 8) * 4);
  int*            csroff = (int*)alloc((size_t)(N + 1) * 4);
  int*            cursor = (int*)alloc((size_t)N * 4);
  int*            count  = (int*)alloc((size_t)N * 4);
  int*            perm   = (int*)alloc((size_t)N * 4);
  int*            bsum   = (int*)alloc(256 * 4);
  int*            dcount = (int*)alloc(512 * 4);
  int*            dcursor= (int*)alloc(512 * 4);
  int*            flag   = (int*)alloc(256);
  unsigned short* WbT1   = (unsigned short*)alloc(256 * 128 * 2);
  unsigned short* WbT2   = (unsigned short*)alloc(64 * 128 * 2);

  // layer-2 packed transforms overlay the (then-dead) xl1p region
  unsigned* xl2p = xl1p;
  unsigned* xr2p = xl1p + (size_t)N * 16;

  const int nscan = (N + 255) / 256;
  const int rsz = (N + 7) / 8;
  const int nch = 256;
  const int ce = (Etot + nch - 1) / nch;
  const int nblk = (N + 255) / 256;

  // ---------------- weight packing ----------------
  hipLaunchKernelGGL(packW_k, dim3((256 * 128 + 255) / 256), dim3(256), 0, stream,
                     Wl1, Wr1, WbT1, 128, 256 * 128);
  hipLaunchKernelGGL(packW_k, dim3((64 * 128 + 255) / 256), dim3(256), 0, stream,
                     Wl2, Wr2, WbT2, 32, 64 * 128);

  // ---------------- CSR build (XCD-partitioned) ----------------
  hipLaunchKernelGGL(detect_idx64, dim3(1), dim3(64), 0, stream, ei, N, flag);
  hipMemsetAsync(count, 0, (size_t)N * 4, stream);
  hipMemsetAsync(dcount, 0, 512 * 4, stream);
  hipLaunchKernelGGL(hist_xcd_k, dim3(8 * nch), dim3(256), 0, stream,
                     ei, flag, count, E, Etot, rsz, N, ce);
  hipLaunchKernelGGL(scan1_k, dim3(nscan), dim3(256), 0, stream, count, bsum, N);
  hipLaunchKernelGGL(scan2_k, dim3(1), dim3(256), 0, stream, bsum, nscan);
  hipLaunchKernelGGL(scan3_k, dim3(nscan), dim3(256), 0, stream, count, bsum, csroff, cursor, N, Etot);
  hipLaunchKernelGGL(scatter_xcd_k, dim3(8 * nch), dim3(256), 0, stream,
                     ei, flag, cursor, bucket, E, Etot, rsz, N, ce);

  // ---------------- degree-equalized node permutation ----------------
  hipLaunchKernelGGL(deg_hist_k, dim3(nblk), dim3(256), 0, stream, csroff, dcount, N);
  hipLaunchKernelGGL(deg_scan_k, dim3(1), dim3(512), 0, stream, dcount, dcursor);
  hipLaunchKernelGGL(deg_scatter_k, dim3(nblk), dim3(256), 0, stream, csroff, dcursor, perm, N);

  // ---------------- layer 1 (pair-interleaved packed layout) ----------------
  hipLaunchKernelGGL((mfma_dual_gemm<256, 128, 64, true>), dim3((N + 63) / 64), dim3(256), 0, stream,
                     x, WbT1, xl1p, xr1p, N);
  hipLaunchKernelGGL(fused_layer1_k, dim3((N + 15) / 16), dim3(256), 0, stream,
                     xl1p, xr1p, csroff, bucket, perm, att1, b1, h1, N);

  // ---------------- layer 2 ----------------
  hipLaunchKernelGGL((mfma_dual_gemm<64, 32, 32, false>), dim3((N + 63) / 64), dim3(256), 0, stream,
                     h1, WbT2, xl2p, xr2p, N);
  hipLaunchKernelGGL(fused_layer2_k, dim3((N + 15) / 16), dim3(256), 0, stream,
                     xl2p, xr2p, csroff, bucket, perm, att2, b2, out, N);
}

// Round 13
// 228.507 us; speedup vs baseline: 2.1864x; 2.1864x over previous
//
#include <hip/hip_runtime.h>

#define NEG 0.2f

typedef __attribute__((ext_vector_type(4))) float f32x4;
typedef __attribute__((ext_vector_type(8))) short bf16x8;

// ---------- bf16 pack/unpack (RNE) ----------
__device__ __forceinline__ float blo(unsigned u) { return __uint_as_float(u << 16); }
__device__ __forceinline__ float bhi(unsigned u) { return __uint_as_float(u & 0xffff0000u); }
__device__ __forceinline__ unsigned bpack(float a, float b) {
  unsigned ua = __float_as_uint(a), ub = __float_as_uint(b);
  unsigned ra = (ua + 0x7fffu + ((ua >> 16) & 1u)) >> 16;
  unsigned rb = (ub + 0x7fffu + ((ub >> 16) & 1u)) >> 16;
  return ra | (rb << 16);
}
__device__ __forceinline__ unsigned short b16(float a) {
  unsigned ua = __float_as_uint(a);
  return (unsigned short)((ua + 0x7fffu + ((ua >> 16) & 1u)) >> 16);
}

// 16-lane xor-butterfly reduce via ds_swizzle (pattern immediate, 3 inst/stage).
__device__ __forceinline__ float red16(float t) {
  t += __int_as_float(__builtin_amdgcn_ds_swizzle(__float_as_int(t), 0x041F));  // xor 1
  t += __int_as_float(__builtin_amdgcn_ds_swizzle(__float_as_int(t), 0x081F));  // xor 2
  t += __int_as_float(__builtin_amdgcn_ds_swizzle(__float_as_int(t), 0x101F));  // xor 4
  t += __int_as_float(__builtin_amdgcn_ds_swizzle(__float_as_int(t), 0x201F));  // xor 8
  return t;
}

// ---------- detect whether edge_index arrived as int64 or int32 ----------
__global__ void detect_idx64(const void* __restrict__ ei, int n_nodes, int* __restrict__ flag) {
  const long long* e64 = (const long long*)ei;
  long long v = e64[threadIdx.x];
  bool ok = (v >= 0 && v < (long long)n_nodes);
  unsigned long long b = __ballot(ok);
  if (threadIdx.x == 0) *flag = (b == ~0ull) ? 1 : 0;
}

__device__ __forceinline__ void get_edge(const void* __restrict__ ei, int is64, int e, int E,
                                         int& src, int& dst) {
  if (e >= E) { src = e - E; dst = e - E; return; }  // self-loops appended
  if (is64) {
    const long long* p = (const long long*)ei;
    src = (int)p[e];
    dst = (int)p[(size_t)E + e];
  } else {
    const int* p = (const int*)ei;
    src = p[e];
    dst = p[E + e];
  }
}

// ---------- XCD-range-partitioned CSR build ----------
__global__ void hist_xcd_k(const void* __restrict__ ei, const int* __restrict__ flag,
                           int* __restrict__ count, int E, int Etot, int rsz, int N, int ce) {
  int r = blockIdx.x & 7, c = blockIdx.x >> 3;
  int lo = r * rsz, hi = min(N, lo + rsz);
  int eend = min(Etot, (c + 1) * ce);
  int is64 = *flag;
  for (int e = c * ce + threadIdx.x; e < eend; e += 256) {
    int src, dst;
    get_edge(ei, is64, e, E, src, dst);
    (void)src;
    if (dst >= lo && dst < hi) atomicAdd(&count[dst], 1);
  }
}

__global__ void scatter_xcd_k(const void* __restrict__ ei, const int* __restrict__ flag,
                              int* __restrict__ cursor, int* __restrict__ bucket,
                              int E, int Etot, int rsz, int N, int ce) {
  int r = blockIdx.x & 7, c = blockIdx.x >> 3;
  int lo = r * rsz, hi = min(N, lo + rsz);
  int eend = min(Etot, (c + 1) * ce);
  int is64 = *flag;
  for (int e = c * ce + threadIdx.x; e < eend; e += 256) {
    int src, dst;
    get_edge(ei, is64, e, E, src, dst);
    if (dst >= lo && dst < hi) {
      int pos = atomicAdd(&cursor[dst], 1);
      bucket[pos] = src;
    }
  }
}

__global__ void scan1_k(const int* __restrict__ count, int* __restrict__ bsum, int n) {
  __shared__ int sd[256];
  int i = blockIdx.x * 256 + threadIdx.x;
  sd[threadIdx.x] = (i < n) ? count[i] : 0;
  __syncthreads();
  for (int o = 128; o; o >>= 1) {
    if (threadIdx.x < o) sd[threadIdx.x] += sd[threadIdx.x + o];
    __syncthreads();
  }
  if (threadIdx.x == 0) bsum[blockIdx.x] = sd[0];
}

__global__ void scan2_k(int* __restrict__ bsum, int nb) {
  __shared__ int sd[256];
  int v = (threadIdx.x < nb) ? bsum[threadIdx.x] : 0;
  sd[threadIdx.x] = v;
  __syncthreads();
  for (int o = 1; o < 256; o <<= 1) {
    int t = (threadIdx.x >= o) ? sd[threadIdx.x - o] : 0;
    __syncthreads();
    sd[threadIdx.x] += t;
    __syncthreads();
  }
  if (threadIdx.x < nb) bsum[threadIdx.x] = sd[threadIdx.x] - v;
}

__global__ void scan3_k(const int* __restrict__ count, const int* __restrict__ bsum,
                        int* __restrict__ off, int* __restrict__ cursor, int n, int etot) {
  __shared__ int sd[256];
  int i = blockIdx.x * 256 + threadIdx.x;
  int v = (i < n) ? count[i] : 0;
  sd[threadIdx.x] = v;
  __syncthreads();
  for (int o = 1; o < 256; o <<= 1) {
    int t = (threadIdx.x >= o) ? sd[threadIdx.x - o] : 0;
    __syncthreads();
    sd[threadIdx.x] += t;
    __syncthreads();
  }
  if (i < n) {
    int ex = bsum[blockIdx.x] + sd[threadIdx.x] - v;
    off[i] = ex;
    cursor[i] = ex;
  }
  if (i == 0) off[n] = etot;
}

// ---------- degree sort, two-level (NO global atomics) ----------
// 1) per-block LDS histogram -> hist2d[bin][blk]
__global__ void deg_hist2_k(const int* __restrict__ off, int* __restrict__ hist2d,
                            int N, int nblk) {
  __shared__ int h[512];
  h[threadIdx.x] = 0; h[threadIdx.x + 256] = 0;
  __syncthreads();
  int i = blockIdx.x * 256 + threadIdx.x;
  if (i < N) {
    int d = off[i + 1] - off[i];
    d = d < 511 ? d : 511;
    atomicAdd(&h[d], 1);   // LDS atomic
  }
  __syncthreads();
  hist2d[(size_t)threadIdx.x * nblk + blockIdx.x] = h[threadIdx.x];
  hist2d[(size_t)(threadIdx.x + 256) * nblk + blockIdx.x] = h[threadIdx.x + 256];
}

// 2) generic exclusive scan over T = 512*nblk elements (bin-major)
__global__ void gscan_sum_k(const int* __restrict__ in, int* __restrict__ bsum, int T) {
  __shared__ int sd[256];
  int base = blockIdx.x * 512;
  int a = (base + threadIdx.x < T) ? in[base + threadIdx.x] : 0;
  int b2 = (base + 256 + threadIdx.x < T) ? in[base + 256 + threadIdx.x] : 0;
  sd[threadIdx.x] = a + b2;
  __syncthreads();
  for (int o = 128; o; o >>= 1) {
    if (threadIdx.x < o) sd[threadIdx.x] += sd[threadIdx.x + o];
    __syncthreads();
  }
  if (threadIdx.x == 0) bsum[blockIdx.x] = sd[0];
}

__global__ void gscan_top_k(int* __restrict__ bsum, int nb) {  // 1 block, 512 thr, nb<=512
  __shared__ int sd[512];
  int t = threadIdx.x;
  int v = (t < nb) ? bsum[t] : 0;
  sd[t] = v;
  __syncthreads();
  for (int o = 1; o < 512; o <<= 1) {
    int x = (t >= o) ? sd[t - o] : 0;
    __syncthreads();
    sd[t] += x;
    __syncthreads();
  }
  if (t < nb) bsum[t] = sd[t] - v;
}

__global__ void gscan_fin_k(const int* __restrict__ in, const int* __restrict__ bsum,
                            int* __restrict__ out, int T) {  // 512 thr/block
  __shared__ int sd[512];
  int base = blockIdx.x * 512;
  int t = threadIdx.x;
  int v = (base + t < T) ? in[base + t] : 0;
  sd[t] = v;
  __syncthreads();
  for (int o = 1; o < 512; o <<= 1) {
    int x = (t >= o) ? sd[t - o] : 0;
    __syncthreads();
    sd[t] += x;
    __syncthreads();
  }
  if (base + t < T) out[base + t] = bsum[blockIdx.x] + sd[t] - v;
}

// 3) scatter with block-local LDS cursors (intra-bin order arbitrary; outputs unaffected)
__global__ void deg_scatter2_k(const int* __restrict__ off, const int* __restrict__ base2d,
                               int* __restrict__ perm, int N, int nblk) {
  __shared__ int cur[512];
  cur[threadIdx.x] = 0; cur[threadIdx.x + 256] = 0;
  __syncthreads();
  int i = blockIdx.x * 256 + threadIdx.x;
  if (i < N) {
    int d = off[i + 1] - off[i];
    d = d < 511 ? d : 511;
    int r = atomicAdd(&cur[d], 1);   // LDS atomic
    perm[base2d[(size_t)d * nblk + blockIdx.x] + r] = i;
  }
}

// ---------- pack [Wl|Wr] (fp32 row-major [128][C]) -> WbT[col][k] bf16 ----------
__global__ void packW_k(const float* __restrict__ Wl, const float* __restrict__ Wr,
                        unsigned short* __restrict__ WbT, int C, int total) {
  int i = blockIdx.x * 256 + threadIdx.x;
  if (i >= total) return;
  int col = i >> 7, k = i & 127;
  float v = (col < C) ? Wl[(size_t)k * C + col] : Wr[(size_t)k * C + (col - C)];
  WbT[i] = b16(v);
}

// ---------- MFMA dual GEMM: [xl|xr] = X(fp32) @ WbT(bf16), K=128 ----------
template <int NCOL, int C, int HS, bool PAIRI>
__global__ void mfma_dual_gemm(const float* __restrict__ X, const unsigned short* __restrict__ WbT,
                               unsigned* __restrict__ xl_p, unsigned* __restrict__ xr_p, int nrows) {
  constexpr int NF = NCOL / 16;
  constexpr int NPM = C / 2;
  constexpr int FPM = C / 16;
  constexpr int FPH = HS / 16;
  constexpr int POFF = HS / 32;
  const int wave = threadIdx.x >> 6;
  const int lane = threadIdx.x & 63;
  const int row0 = blockIdx.x * 64 + wave * 16;
  const int rA = row0 + (lane & 15);
  const int rAc = (rA < nrows) ? rA : (nrows - 1);
  const int kA = (lane >> 4) * 8;
  const int colB = lane & 15;

  f32x4 acc[NF];
#pragma unroll
  for (int f = 0; f < NF; ++f) acc[f] = (f32x4){0.f, 0.f, 0.f, 0.f};

#pragma unroll
  for (int k0 = 0; k0 < 128; k0 += 32) {
    const float* ax = &X[(size_t)rAc * 128 + k0 + kA];
    float4 a0 = *(const float4*)ax;
    float4 a1 = *(const float4*)(ax + 4);
    union { unsigned u[4]; bf16x8 v; } af;
    af.u[0] = bpack(a0.x, a0.y);
    af.u[1] = bpack(a0.z, a0.w);
    af.u[2] = bpack(a1.x, a1.y);
    af.u[3] = bpack(a1.z, a1.w);
#pragma unroll
    for (int nf = 0; nf < NF; ++nf) {
      union { uint4 u4; bf16x8 v; } bf;
      bf.u4 = *(const uint4*)&WbT[(size_t)(nf * 16 + colB) * 128 + k0 + kA];
      acc[nf] = __builtin_amdgcn_mfma_f32_16x16x32_bf16(af.v, bf.v, acc[nf], 0, 0, 0);
    }
  }

#pragma unroll
  for (int mat = 0; mat < 2; ++mat) {
    unsigned* outp = mat ? xr_p : xl_p;
#pragma unroll
    for (int mf = 0; mf < FPM; ++mf) {
      int head = mf / FPH, hf = mf % FPH;
      if (hf >= POFF) continue;
      int f = mat * FPM + mf;
      int pair = hf * 16 + colB;
      int q = PAIRI ? (2 * pair + head) : (head * (HS / 2) + pair);
#pragma unroll
      for (int r = 0; r < 4; ++r) {
        int row = row0 + ((lane >> 4) << 2) + r;
        if (row < nrows) outp[(size_t)row * NPM + q] = bpack(acc[f][r], acc[f + POFF][r]);
      }
    }
  }
}

// ---------- layer 1 fused: 16 lanes per node (4 nodes/wave), degree-sorted ----------
__global__ void fused_layer1_k(const unsigned* __restrict__ xl_p, const unsigned* __restrict__ xr_p,
                               const int* __restrict__ off, const int* __restrict__ bucket,
                               const int* __restrict__ perm,
                               const float* __restrict__ att, const float* __restrict__ b,
                               float* __restrict__ h1, int N) {
  int grp = threadIdx.x >> 4, sub = threadIdx.x & 15;
  int idx = blockIdx.x * 16 + grp;
  if (idx >= N) return;
  int node = perm[idx];
  const int c0 = 2 * sub, c1 = 2 * sub + 1;
  uint4 xr4 = *(const uint4*)&xr_p[(size_t)node * 64 + 4 * sub];
  float xr0 = blo(xr4.x), xr1 = bhi(xr4.x);   // h0: ch c0, c0+32
  float xr2 = blo(xr4.y), xr3 = bhi(xr4.y);   // h1: ch 64+c0, 96+c0
  float xr4f = blo(xr4.z), xr5 = bhi(xr4.z);  // h0: ch c1, c1+32
  float xr6 = blo(xr4.w), xr7 = bhi(xr4.w);   // h1: ch 64+c1, 96+c1
  float at0 = att[c0], at1 = att[c0 + 32], at2 = att[64 + c0], at3 = att[96 + c0];
  float at4 = att[c1], at5 = att[c1 + 32], at6 = att[64 + c1], at7 = att[96 + c1];

  float m0 = -INFINITY, m1 = -INFINITY, s0 = 0.f, s1 = 0.f;
  float o0 = 0.f, o1 = 0.f, o2 = 0.f, o3 = 0.f, o4 = 0.f, o5 = 0.f, o6 = 0.f, o7 = 0.f;
  int j = off[node], jend = off[node + 1];

  auto tpart = [&](uint4 v, float* vv, float& t0, float& t1) {
    vv[0] = blo(v.x); vv[1] = bhi(v.x); vv[2] = blo(v.y); vv[3] = bhi(v.y);
    vv[4] = blo(v.z); vv[5] = bhi(v.z); vv[6] = blo(v.w); vv[7] = bhi(v.w);
    float e0 = vv[0] + xr0;  e0 = fmaxf(e0, NEG * e0);
    float e1 = vv[1] + xr1;  e1 = fmaxf(e1, NEG * e1);
    float e2 = vv[2] + xr2;  e2 = fmaxf(e2, NEG * e2);
    float e3 = vv[3] + xr3;  e3 = fmaxf(e3, NEG * e3);
    float e4 = vv[4] + xr4f; e4 = fmaxf(e4, NEG * e4);
    float e5 = vv[5] + xr5;  e5 = fmaxf(e5, NEG * e5);
    float e6 = vv[6] + xr6;  e6 = fmaxf(e6, NEG * e6);
    float e7 = vv[7] + xr7;  e7 = fmaxf(e7, NEG * e7);
    t0 = fmaf(e0, at0, e1 * at1) + fmaf(e4, at4, e5 * at5);
    t1 = fmaf(e2, at2, e3 * at3) + fmaf(e6, at6, e7 * at7);
  };

  int b0i = bucket[j];
  int b1i = (j + 1 < jend) ? bucket[j + 1] : b0i;
  uint4 v0 = *(const uint4*)&xl_p[(size_t)b0i * 64 + 4 * sub];
  uint4 v1 = *(const uint4*)&xl_p[(size_t)b1i * 64 + 4 * sub];
  bool val1 = (j + 1 < jend);

  for (;;) {
    float va[8], vb[8], t0a, t1a, t0b, t1b;
    tpart(v0, va, t0a, t1a);
    tpart(v1, vb, t0b, t1b);
    if (!val1) { t0b = -1e30f; t1b = -1e30f; }

    int jn = j + 2;
    bool more = jn < jend;
    if (more) {
      int n0 = bucket[jn];
      int n1 = (jn + 1 < jend) ? bucket[jn + 1] : n0;
      v0 = *(const uint4*)&xl_p[(size_t)n0 * 64 + 4 * sub];
      v1 = *(const uint4*)&xl_p[(size_t)n1 * 64 + 4 * sub];
      val1 = (jn + 1 < jend);
    }

    t0a = red16(t0a); t1a = red16(t1a);
    t0b = red16(t0b); t1b = red16(t1b);

    float tm0 = fmaxf(t0a, t0b), tm1 = fmaxf(t1a, t1b);
    if (__any((tm0 > m0 + 8.f) || (tm1 > m1 + 8.f))) {
      float nm0 = fmaxf(m0, tm0), nm1 = fmaxf(m1, tm1);
      float c0r = __expf(m0 - nm0), c1r = __expf(m1 - nm1);
      s0 *= c0r; s1 *= c1r;
      o0 *= c0r; o1 *= c0r; o4 *= c0r; o5 *= c0r;
      o2 *= c1r; o3 *= c1r; o6 *= c1r; o7 *= c1r;
      m0 = nm0; m1 = nm1;
    }
    float p0a = __expf(t0a - m0), p1a = __expf(t1a - m1);
    float p0b = __expf(t0b - m0), p1b = __expf(t1b - m1);
    s0 += p0a + p0b;
    s1 += p1a + p1b;
    o0 = fmaf(p0a, va[0], fmaf(p0b, vb[0], o0));
    o1 = fmaf(p0a, va[1], fmaf(p0b, vb[1], o1));
    o4 = fmaf(p0a, va[4], fmaf(p0b, vb[4], o4));
    o5 = fmaf(p0a, va[5], fmaf(p0b, vb[5], o5));
    o2 = fmaf(p1a, va[2], fmaf(p1b, vb[2], o2));
    o3 = fmaf(p1a, va[3], fmaf(p1b, vb[3], o3));
    o6 = fmaf(p1a, va[6], fmaf(p1b, vb[6], o6));
    o7 = fmaf(p1a, va[7], fmaf(p1b, vb[7], o7));
    if (!more) break;
    j = jn;
  }

  float i0 = 1.f / s0, i1 = 1.f / s1;
  auto elu = [](float r) { return r > 0.f ? r : __expf(r) - 1.f; };
  float* row = h1 + (size_t)node * 128;
  float2 w;
  w.x = elu(fmaf(o0, i0, b[c0]));       w.y = elu(fmaf(o4, i0, b[c1]));
  *(float2*)&row[c0] = w;
  w.x = elu(fmaf(o1, i0, b[c0 + 32]));  w.y = elu(fmaf(o5, i0, b[c1 + 32]));
  *(float2*)&row[c0 + 32] = w;
  w.x = elu(fmaf(o2, i1, b[64 + c0])); w.y = elu(fmaf(o6, i1, b[64 + c1]));
  *(float2*)&row[64 + c0] = w;
  w.x = elu(fmaf(o3, i1, b[96 + c0])); w.y = elu(fmaf(o7, i1, b[96 + c1]));
  *(float2*)&row[96 + c0] = w;
}

// ---------- layer 2 fused: 16 lanes per node, degree-sorted ----------
__global__ void fused_layer2_k(const unsigned* __restrict__ xl_p, const unsigned* __restrict__ xr_p,
                               const int* __restrict__ off, const int* __restrict__ bucket,
                               const int* __restrict__ perm,
                               const float* __restrict__ att, const float* __restrict__ b,
                               float* __restrict__ out, int N) {
  int idx = blockIdx.x * 16 + (threadIdx.x >> 4);
  int lane = threadIdx.x & 15;
  if (idx >= N) return;
  int node = perm[idx];
  unsigned xru = xr_p[(size_t)node * 16 + lane];
  float xr_a = blo(xru), xr_b = bhi(xru);
  float att_a = att[lane], att_b = att[lane + 16];
  float m = -INFINITY, s = 0.f, oa = 0.f, ob = 0.f;
  int j0 = off[node], jend = off[node + 1];

  auto tpart = [&](unsigned vu, float& va, float& vb) {
    va = blo(vu); vb = bhi(vu);
    float ea = va + xr_a; ea = fmaxf(ea, NEG * ea);
    float eb = vb + xr_b; eb = fmaxf(eb, NEG * eb);
    return fmaf(ea, att_a, eb * att_b);
  };

  auto upd4 = [&](const unsigned* v, int nvalid) {
    float va0, vb0, va1, vb1, va2, vb2, va3, vb3;
    float t0 = tpart(v[0], va0, vb0);
    float t1 = tpart(v[1], va1, vb1);
    float t2 = tpart(v[2], va2, vb2);
    float t3 = tpart(v[3], va3, vb3);
    if (nvalid < 4) {
      if (nvalid <= 1) t1 = -1e30f;
      if (nvalid <= 2) t2 = -1e30f;
      t3 = -1e30f;
    }
    t0 = red16(t0); t1 = red16(t1); t2 = red16(t2); t3 = red16(t3);
    float tm = fmaxf(fmaxf(t0, t1), fmaxf(t2, t3));
    if (__any(tm > m + 8.f)) {
      float nm = fmaxf(m, tm);
      float c = __expf(m - nm);
      s *= c; oa *= c; ob *= c;
      m = nm;
    }
    float p0 = __expf(t0 - m), p1 = __expf(t1 - m);
    float p2 = __expf(t2 - m), p3 = __expf(t3 - m);
    s += (p0 + p1) + (p2 + p3);
    oa = fmaf(p0, va0, fmaf(p1, va1, fmaf(p2, va2, fmaf(p3, va3, oa))));
    ob = fmaf(p0, vb0, fmaf(p1, vb1, fmaf(p2, vb2, fmaf(p3, vb3, ob))));
  };

  unsigned cv[4], nv[4];
  int deg = jend - j0;
#pragma unroll
  for (int k = 0; k < 4; ++k) {
    int idx2 = j0 + ((k < deg) ? k : 0);
    cv[k] = xl_p[(size_t)bucket[idx2] * 16 + lane];
  }
  int j = j0;
  for (;;) {
    int jn = j + 4;
    bool more = jn < jend;
    if (more) {
      int rem = jend - jn;
#pragma unroll
      for (int k = 0; k < 4; ++k) {
        int idx2 = jn + ((k < rem) ? k : 0);
        nv[k] = xl_p[(size_t)bucket[idx2] * 16 + lane];
      }
    }
    int nvalid = jend - j; if (nvalid > 4) nvalid = 4;
    upd4(cv, nvalid);
    if (!more) break;
#pragma unroll
    for (int k = 0; k < 4; ++k) cv[k] = nv[k];
    j = jn;
  }

  float inv = 1.f / s;
  out[(size_t)node * 32 + lane]      = fmaf(oa, inv, b[lane]);
  out[(size_t)node * 32 + 16 + lane] = fmaf(ob, inv, b[lane + 16]);
}

extern "C" void kernel_launch(void* const* d_in, const int* in_sizes, int n_in,
                              void* d_out, int out_size, void* d_ws, size_t ws_size,
                              hipStream_t stream) {
  const float* x    = (const float*)d_in[0];
  const void*  ei   = d_in[1];
  const float* Wl1  = (const float*)d_in[2];
  const float* Wr1  = (const float*)d_in[3];
  const float* att1 = (const float*)d_in[4];
  const float* b1   = (const float*)d_in[5];
  const float* Wl2  = (const float*)d_in[6];
  const float* Wr2  = (const float*)d_in[7];
  const float* att2 = (const float*)d_in[8];
  const float* b2   = (const float*)d_in[9];

  const int N = in_sizes[0] / 128;
  const int E = in_sizes[1] / 2;
  const int Etot = E + N;
  float* out = (float*)d_out;
  (void)out_size; (void)n_in; (void)ws_size;

  // ---------------- workspace layout ----------------
  char* ws = (char*)d_ws;
  size_t off_b = 0;
  auto alloc = [&](size_t bytes) {
    void* p = ws + off_b;
    off_b += (bytes + 255) & ~(size_t)255;
    return p;
  };
  const int nblk = (N + 255) / 256;
  unsigned*       xl1p   = (unsigned*)alloc((size_t)N * 64 * 4);  // packed bf16 pairs
  unsigned*       xr1p   = (unsigned*)alloc((size_t)N * 64 * 4);
  float*          h1     = (float*)alloc((size_t)N * 128 * 4);
  int*            bucket = (int*)alloc((size_t)(Etot + 8) * 4);
  int*            csroff = (int*)alloc((size_t)(N + 1) * 4);
  int*            cursor = (int*)alloc((size_t)N * 4);
  int*            count  = (int*)alloc((size_t)N * 4);
  int*            perm   = (int*)alloc((size_t)N * 4);
  int*            bsum   = (int*)alloc(256 * 4);
  int*            hist2d = (int*)alloc((size_t)512 * nblk * 4);
  int*            base2d = (int*)alloc((size_t)512 * nblk * 4);
  int*            gbsum  = (int*)alloc(512 * 4);
  int*            flag   = (int*)alloc(256);
  unsigned short* WbT1   = (unsigned short*)alloc(256 * 128 * 2);
  unsigned short* WbT2   = (unsigned short*)alloc(64 * 128 * 2);

  // layer-2 packed transforms overlay the (then-dead) xl1p region
  unsigned* xl2p = xl1p;
  unsigned* xr2p = xl1p + (size_t)N * 16;

  const int nscan = (N + 255) / 256;
  const int rsz = (N + 7) / 8;
  const int nch = 256;
  const int ce = (Etot + nch - 1) / nch;
  const int T = 512 * nblk;

  // ---------------- weight packing ----------------
  hipLaunchKernelGGL(packW_k, dim3((256 * 128 + 255) / 256), dim3(256), 0, stream,
                     Wl1, Wr1, WbT1, 128, 256 * 128);
  hipLaunchKernelGGL(packW_k, dim3((64 * 128 + 255) / 256), dim3(256), 0, stream,
                     Wl2, Wr2, WbT2, 32, 64 * 128);

  // ---------------- CSR build (XCD-partitioned) ----------------
  hipLaunchKernelGGL(detect_idx64, dim3(1), dim3(64), 0, stream, ei, N, flag);
  hipMemsetAsync(count, 0, (size_t)N * 4, stream);
  hipLaunchKernelGGL(hist_xcd_k, dim3(8 * nch), dim3(256), 0, stream,
                     ei, flag, count, E, Etot, rsz, N, ce);
  hipLaunchKernelGGL(scan1_k, dim3(nscan), dim3(256), 0, stream, count, bsum, N);
  hipLaunchKernelGGL(scan2_k, dim3(1), dim3(256), 0, stream, bsum, nscan);
  hipLaunchKernelGGL(scan3_k, dim3(nscan), dim3(256), 0, stream, count, bsum, csroff, cursor, N, Etot);
  hipLaunchKernelGGL(scatter_xcd_k, dim3(8 * nch), dim3(256), 0, stream,
                     ei, flag, cursor, bucket, E, Etot, rsz, N, ce);

  // ---------------- degree-equalized node permutation (no global atomics) ----------------
  hipLaunchKernelGGL(deg_hist2_k, dim3(nblk), dim3(256), 0, stream, csroff, hist2d, N, nblk);
  hipLaunchKernelGGL(gscan_sum_k, dim3(nblk), dim3(256), 0, stream, hist2d, gbsum, T);
  hipLaunchKernelGGL(gscan_top_k, dim3(1), dim3(512), 0, stream, gbsum, nblk);
  hipLaunchKernelGGL(gscan_fin_k, dim3(nblk), dim3(512), 0, stream, hist2d, gbsum, base2d, T);
  hipLaunchKernelGGL(deg_scatter2_k, dim3(nblk), dim3(256), 0, stream, csroff, base2d, perm, N, nblk);

  // ---------------- layer 1 (pair-interleaved packed layout) ----------------
  hipLaunchKernelGGL((mfma_dual_gemm<256, 128, 64, true>), dim3((N + 63) / 64), dim3(256), 0, stream,
                     x, WbT1, xl1p, xr1p, N);
  hipLaunchKernelGGL(fused_layer1_k, dim3((N + 15) / 16), dim3(256), 0, stream,
                     xl1p, xr1p, csroff, bucket, perm, att1, b1, h1, N);

  // ---------------- layer 2 ----------------
  hipLaunchKernelGGL((mfma_dual_gemm<64, 32, 32, false>), dim3((N + 63) / 64), dim3(256), 0, stream,
                     h1, WbT2, xl2p, xr2p, N);
  hipLaunchKernelGGL(fused_layer2_k, dim3((N + 15) / 16), dim3(256), 0, stream,
                     xl2p, xr2p, csroff, bucket, perm, att2, b2, out, N);
}

// Round 14
// 223.386 us; speedup vs baseline: 2.2366x; 1.0229x over previous
//
#include <hip/hip_runtime.h>

#define NEG 0.2f

typedef __attribute__((ext_vector_type(4))) float f32x4;
typedef __attribute__((ext_vector_type(8))) short bf16x8;

// ---------- bf16 pack/unpack (RNE) ----------
__device__ __forceinline__ float blo(unsigned u) { return __uint_as_float(u << 16); }
__device__ __forceinline__ float bhi(unsigned u) { return __uint_as_float(u & 0xffff0000u); }
__device__ __forceinline__ unsigned bpack(float a, float b) {
  unsigned ua = __float_as_uint(a), ub = __float_as_uint(b);
  unsigned ra = (ua + 0x7fffu + ((ua >> 16) & 1u)) >> 16;
  unsigned rb = (ub + 0x7fffu + ((ub >> 16) & 1u)) >> 16;
  return ra | (rb << 16);
}
__device__ __forceinline__ unsigned short b16(float a) {
  unsigned ua = __float_as_uint(a);
  return (unsigned short)((ua + 0x7fffu + ((ua >> 16) & 1u)) >> 16);
}

// 16-lane xor-butterfly reduce via ds_swizzle (pattern immediate, 3 inst/stage).
__device__ __forceinline__ float red16(float t) {
  t += __int_as_float(__builtin_amdgcn_ds_swizzle(__float_as_int(t), 0x041F));  // xor 1
  t += __int_as_float(__builtin_amdgcn_ds_swizzle(__float_as_int(t), 0x081F));  // xor 2
  t += __int_as_float(__builtin_amdgcn_ds_swizzle(__float_as_int(t), 0x101F));  // xor 4
  t += __int_as_float(__builtin_amdgcn_ds_swizzle(__float_as_int(t), 0x201F));  // xor 8
  return t;
}

// ---------- detect whether edge_index arrived as int64 or int32 ----------
__global__ void detect_idx64(const void* __restrict__ ei, int n_nodes, int* __restrict__ flag) {
  const long long* e64 = (const long long*)ei;
  long long v = e64[threadIdx.x];
  bool ok = (v >= 0 && v < (long long)n_nodes);
  unsigned long long b = __ballot(ok);
  if (threadIdx.x == 0) *flag = (b == ~0ull) ? 1 : 0;
}

__device__ __forceinline__ void get_edge(const void* __restrict__ ei, int is64, int e, int E,
                                         int& src, int& dst) {
  if (e >= E) { src = e - E; dst = e - E; return; }  // self-loops appended
  if (is64) {
    const long long* p = (const long long*)ei;
    src = (int)p[e];
    dst = (int)p[(size_t)E + e];
  } else {
    const int* p = (const int*)ei;
    src = p[e];
    dst = p[E + e];
  }
}

// ---------- one-pass conversion to compact int32 (self-loops materialized) ----------
__global__ void convert_k(const void* __restrict__ ei, const int* __restrict__ flag,
                          int* __restrict__ esrc, int* __restrict__ edst, int E, int Etot) {
  int e = blockIdx.x * 256 + threadIdx.x;
  if (e >= Etot) return;
  int src, dst;
  get_edge(ei, *flag, e, E, src, dst);
  esrc[e] = src;
  edst[e] = dst;
}

// ---------- XCD-range-partitioned CSR build (compact int32 input) ----------
__global__ void hist_xcd_k(const int* __restrict__ edst, int* __restrict__ count,
                           int Etot, int rsz, int N, int ce) {
  int r = blockIdx.x & 7, c = blockIdx.x >> 3;
  int lo = r * rsz, hi = min(N, lo + rsz);
  int eend = min(Etot, (c + 1) * ce);
  for (int e = c * ce + threadIdx.x; e < eend; e += 256) {
    int dst = edst[e];
    if (dst >= lo && dst < hi) atomicAdd(&count[dst], 1);
  }
}

__global__ void scatter_xcd_k(const int* __restrict__ esrc, const int* __restrict__ edst,
                              int* __restrict__ cursor, int* __restrict__ bucket,
                              int Etot, int rsz, int N, int ce) {
  int r = blockIdx.x & 7, c = blockIdx.x >> 3;
  int lo = r * rsz, hi = min(N, lo + rsz);
  int eend = min(Etot, (c + 1) * ce);
  for (int e = c * ce + threadIdx.x; e < eend; e += 256) {
    int dst = edst[e];
    if (dst >= lo && dst < hi) {
      int pos = atomicAdd(&cursor[dst], 1);
      bucket[pos] = esrc[e];
    }
  }
}

__global__ void scan1_k(const int* __restrict__ count, int* __restrict__ bsum, int n) {
  __shared__ int sd[256];
  int i = blockIdx.x * 256 + threadIdx.x;
  sd[threadIdx.x] = (i < n) ? count[i] : 0;
  __syncthreads();
  for (int o = 128; o; o >>= 1) {
    if (threadIdx.x < o) sd[threadIdx.x] += sd[threadIdx.x + o];
    __syncthreads();
  }
  if (threadIdx.x == 0) bsum[blockIdx.x] = sd[0];
}

__global__ void scan2_k(int* __restrict__ bsum, int nb) {
  __shared__ int sd[256];
  int v = (threadIdx.x < nb) ? bsum[threadIdx.x] : 0;
  sd[threadIdx.x] = v;
  __syncthreads();
  for (int o = 1; o < 256; o <<= 1) {
    int t = (threadIdx.x >= o) ? sd[threadIdx.x - o] : 0;
    __syncthreads();
    sd[threadIdx.x] += t;
    __syncthreads();
  }
  if (threadIdx.x < nb) bsum[threadIdx.x] = sd[threadIdx.x] - v;
}

__global__ void scan3_k(const int* __restrict__ count, const int* __restrict__ bsum,
                        int* __restrict__ off, int* __restrict__ cursor, int n, int etot) {
  __shared__ int sd[256];
  int i = blockIdx.x * 256 + threadIdx.x;
  int v = (i < n) ? count[i] : 0;
  sd[threadIdx.x] = v;
  __syncthreads();
  for (int o = 1; o < 256; o <<= 1) {
    int t = (threadIdx.x >= o) ? sd[threadIdx.x - o] : 0;
    __syncthreads();
    sd[threadIdx.x] += t;
    __syncthreads();
  }
  if (i < n) {
    int ex = bsum[blockIdx.x] + sd[threadIdx.x] - v;
    off[i] = ex;
    cursor[i] = ex;
  }
  if (i == 0) off[n] = etot;
}

// ---------- degree sort, DESCENDING (LPT), two-level, no global atomics ----------
__global__ void deg_hist2_k(const int* __restrict__ off, int* __restrict__ hist2d,
                            int N, int nblk) {
  __shared__ int h[256];
  h[threadIdx.x] = 0;
  __syncthreads();
  int i = blockIdx.x * 256 + threadIdx.x;
  if (i < N) {
    int d = off[i + 1] - off[i];
    d = d < 255 ? d : 255;
    atomicAdd(&h[255 - d], 1);   // LDS atomic; bin 0 = highest degree
  }
  __syncthreads();
  hist2d[(size_t)threadIdx.x * nblk + blockIdx.x] = h[threadIdx.x];
}

__global__ void gscan_sum_k(const int* __restrict__ in, int* __restrict__ bsum, int T) {
  __shared__ int sd[256];
  int base = blockIdx.x * 512;
  int a = (base + threadIdx.x < T) ? in[base + threadIdx.x] : 0;
  int b2 = (base + 256 + threadIdx.x < T) ? in[base + 256 + threadIdx.x] : 0;
  sd[threadIdx.x] = a + b2;
  __syncthreads();
  for (int o = 128; o; o >>= 1) {
    if (threadIdx.x < o) sd[threadIdx.x] += sd[threadIdx.x + o];
    __syncthreads();
  }
  if (threadIdx.x == 0) bsum[blockIdx.x] = sd[0];
}

__global__ void gscan_top_k(int* __restrict__ bsum, int nb) {  // 1 block, 512 thr, nb<=512
  __shared__ int sd[512];
  int t = threadIdx.x;
  int v = (t < nb) ? bsum[t] : 0;
  sd[t] = v;
  __syncthreads();
  for (int o = 1; o < 512; o <<= 1) {
    int x = (t >= o) ? sd[t - o] : 0;
    __syncthreads();
    sd[t] += x;
    __syncthreads();
  }
  if (t < nb) bsum[t] = sd[t] - v;
}

__global__ void gscan_fin_k(const int* __restrict__ in, const int* __restrict__ bsum,
                            int* __restrict__ out, int T) {  // 512 thr/block
  __shared__ int sd[512];
  int base = blockIdx.x * 512;
  int t = threadIdx.x;
  int v = (base + t < T) ? in[base + t] : 0;
  sd[t] = v;
  __syncthreads();
  for (int o = 1; o < 512; o <<= 1) {
    int x = (t >= o) ? sd[t - o] : 0;
    __syncthreads();
    sd[t] += x;
    __syncthreads();
  }
  if (base + t < T) out[base + t] = bsum[blockIdx.x] + sd[t] - v;
}

__global__ void deg_scatter2_k(const int* __restrict__ off, const int* __restrict__ base2d,
                               int* __restrict__ perm, int N, int nblk) {
  __shared__ int cur[256];
  cur[threadIdx.x] = 0;
  __syncthreads();
  int i = blockIdx.x * 256 + threadIdx.x;
  if (i < N) {
    int d = off[i + 1] - off[i];
    d = d < 255 ? d : 255;
    int db = 255 - d;
    int r = atomicAdd(&cur[db], 1);   // LDS atomic
    perm[base2d[(size_t)db * nblk + blockIdx.x] + r] = i;
  }
}

// ---------- pack weights: [Wl1|Wr1] and [Wl2|Wr2] -> bf16 B^T, one kernel ----------
__global__ void packW2_k(const float* __restrict__ Wl1, const float* __restrict__ Wr1,
                         const float* __restrict__ Wl2, const float* __restrict__ Wr2,
                         unsigned short* __restrict__ WbT1, unsigned short* __restrict__ WbT2) {
  int i = blockIdx.x * 256 + threadIdx.x;   // over 320*128
  if (i >= 320 * 128) return;
  int col = i >> 7, k = i & 127;
  if (col < 256) {
    float v = (col < 128) ? Wl1[(size_t)k * 128 + col] : Wr1[(size_t)k * 128 + (col - 128)];
    WbT1[i] = b16(v);
  } else {
    int c2 = col - 256;   // 0..63
    float v = (c2 < 32) ? Wl2[(size_t)k * 32 + c2] : Wr2[(size_t)k * 32 + (c2 - 32)];
    WbT2[(size_t)c2 * 128 + k] = b16(v);
  }
}

// ---------- MFMA dual GEMM: [xl|xr] = X(fp32) @ WbT(bf16), K=128 ----------
template <int NCOL, int C, int HS, bool PAIRI>
__global__ void mfma_dual_gemm(const float* __restrict__ X, const unsigned short* __restrict__ WbT,
                               unsigned* __restrict__ xl_p, unsigned* __restrict__ xr_p, int nrows) {
  constexpr int NF = NCOL / 16;
  constexpr int NPM = C / 2;
  constexpr int FPM = C / 16;
  constexpr int FPH = HS / 16;
  constexpr int POFF = HS / 32;
  const int wave = threadIdx.x >> 6;
  const int lane = threadIdx.x & 63;
  const int row0 = blockIdx.x * 64 + wave * 16;
  const int rA = row0 + (lane & 15);
  const int rAc = (rA < nrows) ? rA : (nrows - 1);
  const int kA = (lane >> 4) * 8;
  const int colB = lane & 15;

  f32x4 acc[NF];
#pragma unroll
  for (int f = 0; f < NF; ++f) acc[f] = (f32x4){0.f, 0.f, 0.f, 0.f};

#pragma unroll
  for (int k0 = 0; k0 < 128; k0 += 32) {
    const float* ax = &X[(size_t)rAc * 128 + k0 + kA];
    float4 a0 = *(const float4*)ax;
    float4 a1 = *(const float4*)(ax + 4);
    union { unsigned u[4]; bf16x8 v; } af;
    af.u[0] = bpack(a0.x, a0.y);
    af.u[1] = bpack(a0.z, a0.w);
    af.u[2] = bpack(a1.x, a1.y);
    af.u[3] = bpack(a1.z, a1.w);
#pragma unroll
    for (int nf = 0; nf < NF; ++nf) {
      union { uint4 u4; bf16x8 v; } bf;
      bf.u4 = *(const uint4*)&WbT[(size_t)(nf * 16 + colB) * 128 + k0 + kA];
      acc[nf] = __builtin_amdgcn_mfma_f32_16x16x32_bf16(af.v, bf.v, acc[nf], 0, 0, 0);
    }
  }

#pragma unroll
  for (int mat = 0; mat < 2; ++mat) {
    unsigned* outp = mat ? xr_p : xl_p;
#pragma unroll
    for (int mf = 0; mf < FPM; ++mf) {
      int head = mf / FPH, hf = mf % FPH;
      if (hf >= POFF) continue;
      int f = mat * FPM + mf;
      int pair = hf * 16 + colB;
      int q = PAIRI ? (2 * pair + head) : (head * (HS / 2) + pair);
#pragma unroll
      for (int r = 0; r < 4; ++r) {
        int row = row0 + ((lane >> 4) << 2) + r;
        if (row < nrows) outp[(size_t)row * NPM + q] = bpack(acc[f][r], acc[f + POFF][r]);
      }
    }
  }
}

// ---------- layer 1 fused: 16 lanes/node, desc-degree perm, depth-2 pipeline ----------
__global__ void fused_layer1_k(const unsigned* __restrict__ xl_p, const unsigned* __restrict__ xr_p,
                               const int* __restrict__ off, const int* __restrict__ bucket,
                               const int* __restrict__ perm,
                               const float* __restrict__ att, const float* __restrict__ b,
                               float* __restrict__ h1, int N) {
  int grp = threadIdx.x >> 4, sub = threadIdx.x & 15;
  int idx = blockIdx.x * 16 + grp;
  if (idx >= N) return;
  int node = perm[idx];
  const int c0 = 2 * sub, c1 = 2 * sub + 1;
  uint4 xr4 = *(const uint4*)&xr_p[(size_t)node * 64 + 4 * sub];
  float xr0 = blo(xr4.x), xr1 = bhi(xr4.x);   // h0: ch c0, c0+32
  float xr2 = blo(xr4.y), xr3 = bhi(xr4.y);   // h1: ch 64+c0, 96+c0
  float xr4f = blo(xr4.z), xr5 = bhi(xr4.z);  // h0: ch c1, c1+32
  float xr6 = blo(xr4.w), xr7 = bhi(xr4.w);   // h1: ch 64+c1, 96+c1
  float at0 = att[c0], at1 = att[c0 + 32], at2 = att[64 + c0], at3 = att[96 + c0];
  float at4 = att[c1], at5 = att[c1 + 32], at6 = att[64 + c1], at7 = att[96 + c1];

  float m0 = -INFINITY, m1 = -INFINITY, s0 = 0.f, s1 = 0.f;
  float o0 = 0.f, o1 = 0.f, o2 = 0.f, o3 = 0.f, o4 = 0.f, o5 = 0.f, o6 = 0.f, o7 = 0.f;
  int j = off[node], jend = off[node + 1];

  auto tpart = [&](uint4 v, float* vv, float& t0, float& t1) {
    vv[0] = blo(v.x); vv[1] = bhi(v.x); vv[2] = blo(v.y); vv[3] = bhi(v.y);
    vv[4] = blo(v.z); vv[5] = bhi(v.z); vv[6] = blo(v.w); vv[7] = bhi(v.w);
    float e0 = vv[0] + xr0;  e0 = fmaxf(e0, NEG * e0);
    float e1 = vv[1] + xr1;  e1 = fmaxf(e1, NEG * e1);
    float e2 = vv[2] + xr2;  e2 = fmaxf(e2, NEG * e2);
    float e3 = vv[3] + xr3;  e3 = fmaxf(e3, NEG * e3);
    float e4 = vv[4] + xr4f; e4 = fmaxf(e4, NEG * e4);
    float e5 = vv[5] + xr5;  e5 = fmaxf(e5, NEG * e5);
    float e6 = vv[6] + xr6;  e6 = fmaxf(e6, NEG * e6);
    float e7 = vv[7] + xr7;  e7 = fmaxf(e7, NEG * e7);
    t0 = fmaf(e0, at0, e1 * at1) + fmaf(e4, at4, e5 * at5);
    t1 = fmaf(e2, at2, e3 * at3) + fmaf(e6, at6, e7 * at7);
  };

  auto LD = [&](int jj, uint4& a, uint4& bq, int& cnt) {
    int i0 = bucket[jj];
    bool two = (jj + 1 < jend);
    int i1 = two ? bucket[jj + 1] : i0;
    a  = *(const uint4*)&xl_p[(size_t)i0 * 64 + 4 * sub];
    bq = *(const uint4*)&xl_p[(size_t)i1 * 64 + 4 * sub];
    cnt = two ? 2 : 1;
  };

  uint4 p0a, p0b, p1a, p1b;
  int cnt0 = 0, cnt1 = 0;
  LD(j, p0a, p0b, cnt0);
  bool have1 = (j + 2 < jend);
  if (have1) LD(j + 2, p1a, p1b, cnt1);

  for (;;) {
    bool have2 = (j + 4 < jend);
    uint4 qa, qb;
    int cntq = 0;
    if (have2) LD(j + 4, qa, qb, cntq);   // depth-2 prefetch

    float va[8], vb[8], t0a, t1a, t0b, t1b;
    tpart(p0a, va, t0a, t1a);
    tpart(p0b, vb, t0b, t1b);
    if (cnt0 < 2) { t0b = -1e30f; t1b = -1e30f; }

    t0a = red16(t0a); t1a = red16(t1a);
    t0b = red16(t0b); t1b = red16(t1b);

    float tm0 = fmaxf(t0a, t0b), tm1 = fmaxf(t1a, t1b);
    if (__any((tm0 > m0 + 8.f) || (tm1 > m1 + 8.f))) {
      float nm0 = fmaxf(m0, tm0), nm1 = fmaxf(m1, tm1);
      float c0r = __expf(m0 - nm0), c1r = __expf(m1 - nm1);
      s0 *= c0r; s1 *= c1r;
      o0 *= c0r; o1 *= c0r; o4 *= c0r; o5 *= c0r;
      o2 *= c1r; o3 *= c1r; o6 *= c1r; o7 *= c1r;
      m0 = nm0; m1 = nm1;
    }
    float p0a_e = __expf(t0a - m0), p1a_e = __expf(t1a - m1);
    float p0b_e = __expf(t0b - m0), p1b_e = __expf(t1b - m1);
    s0 += p0a_e + p0b_e;
    s1 += p1a_e + p1b_e;
    o0 = fmaf(p0a_e, va[0], fmaf(p0b_e, vb[0], o0));
    o1 = fmaf(p0a_e, va[1], fmaf(p0b_e, vb[1], o1));
    o4 = fmaf(p0a_e, va[4], fmaf(p0b_e, vb[4], o4));
    o5 = fmaf(p0a_e, va[5], fmaf(p0b_e, vb[5], o5));
    o2 = fmaf(p1a_e, va[2], fmaf(p1b_e, vb[2], o2));
    o3 = fmaf(p1a_e, va[3], fmaf(p1b_e, vb[3], o3));
    o6 = fmaf(p1a_e, va[6], fmaf(p1b_e, vb[6], o6));
    o7 = fmaf(p1a_e, va[7], fmaf(p1b_e, vb[7], o7));

    if (!have1) break;
    p0a = p1a; p0b = p1b; cnt0 = cnt1;
    if (have2) { p1a = qa; p1b = qb; cnt1 = cntq; }
    have1 = have2;
    j += 2;
  }

  float i0 = 1.f / s0, i1 = 1.f / s1;
  auto elu = [](float r) { return r > 0.f ? r : __expf(r) - 1.f; };
  float* row = h1 + (size_t)node * 128;
  float2 w;
  w.x = elu(fmaf(o0, i0, b[c0]));       w.y = elu(fmaf(o4, i0, b[c1]));
  *(float2*)&row[c0] = w;
  w.x = elu(fmaf(o1, i0, b[c0 + 32]));  w.y = elu(fmaf(o5, i0, b[c1 + 32]));
  *(float2*)&row[c0 + 32] = w;
  w.x = elu(fmaf(o2, i1, b[64 + c0])); w.y = elu(fmaf(o6, i1, b[64 + c1]));
  *(float2*)&row[64 + c0] = w;
  w.x = elu(fmaf(o3, i1, b[96 + c0])); w.y = elu(fmaf(o7, i1, b[96 + c1]));
  *(float2*)&row[96 + c0] = w;
}

// ---------- layer 2 fused: 16 lanes per node, desc-degree perm ----------
__global__ void fused_layer2_k(const unsigned* __restrict__ xl_p, const unsigned* __restrict__ xr_p,
                               const int* __restrict__ off, const int* __restrict__ bucket,
                               const int* __restrict__ perm,
                               const float* __restrict__ att, const float* __restrict__ b,
                               float* __restrict__ out, int N) {
  int idx = blockIdx.x * 16 + (threadIdx.x >> 4);
  int lane = threadIdx.x & 15;
  if (idx >= N) return;
  int node = perm[idx];
  unsigned xru = xr_p[(size_t)node * 16 + lane];
  float xr_a = blo(xru), xr_b = bhi(xru);
  float att_a = att[lane], att_b = att[lane + 16];
  float m = -INFINITY, s = 0.f, oa = 0.f, ob = 0.f;
  int j0 = off[node], jend = off[node + 1];

  auto tpart = [&](unsigned vu, float& va, float& vb) {
    va = blo(vu); vb = bhi(vu);
    float ea = va + xr_a; ea = fmaxf(ea, NEG * ea);
    float eb = vb + xr_b; eb = fmaxf(eb, NEG * eb);
    return fmaf(ea, att_a, eb * att_b);
  };

  auto upd4 = [&](const unsigned* v, int nvalid) {
    float va0, vb0, va1, vb1, va2, vb2, va3, vb3;
    float t0 = tpart(v[0], va0, vb0);
    float t1 = tpart(v[1], va1, vb1);
    float t2 = tpart(v[2], va2, vb2);
    float t3 = tpart(v[3], va3, vb3);
    if (nvalid < 4) {
      if (nvalid <= 1) t1 = -1e30f;
      if (nvalid <= 2) t2 = -1e30f;
      t3 = -1e30f;
    }
    t0 = red16(t0); t1 = red16(t1); t2 = red16(t2); t3 = red16(t3);
    float tm = fmaxf(fmaxf(t0, t1), fmaxf(t2, t3));
    if (__any(tm > m + 8.f)) {
      float nm = fmaxf(m, tm);
      float c = __expf(m - nm);
      s *= c; oa *= c; ob *= c;
      m = nm;
    }
    float p0 = __expf(t0 - m), p1 = __expf(t1 - m);
    float p2 = __expf(t2 - m), p3 = __expf(t3 - m);
    s += (p0 + p1) + (p2 + p3);
    oa = fmaf(p0, va0, fmaf(p1, va1, fmaf(p2, va2, fmaf(p3, va3, oa))));
    ob = fmaf(p0, vb0, fmaf(p1, vb1, fmaf(p2, vb2, fmaf(p3, vb3, ob))));
  };

  unsigned cv[4], nv[4];
  int deg = jend - j0;
#pragma unroll
  for (int k = 0; k < 4; ++k) {
    int idx2 = j0 + ((k < deg) ? k : 0);
    cv[k] = xl_p[(size_t)bucket[idx2] * 16 + lane];
  }
  int j = j0;
  for (;;) {
    int jn = j + 4;
    bool more = jn < jend;
    if (more) {
      int rem = jend - jn;
#pragma unroll
      for (int k = 0; k < 4; ++k) {
        int idx2 = jn + ((k < rem) ? k : 0);
        nv[k] = xl_p[(size_t)bucket[idx2] * 16 + lane];
      }
    }
    int nvalid = jend - j; if (nvalid > 4) nvalid = 4;
    upd4(cv, nvalid);
    if (!more) break;
#pragma unroll
    for (int k = 0; k < 4; ++k) cv[k] = nv[k];
    j = jn;
  }

  float inv = 1.f / s;
  out[(size_t)node * 32 + lane]      = fmaf(oa, inv, b[lane]);
  out[(size_t)node * 32 + 16 + lane] = fmaf(ob, inv, b[lane + 16]);
}

extern "C" void kernel_launch(void* const* d_in, const int* in_sizes, int n_in,
                              void* d_out, int out_size, void* d_ws, size_t ws_size,
                              hipStream_t stream) {
  const float* x    = (const float*)d_in[0];
  const void*  ei   = d_in[1];
  const float* Wl1  = (const float*)d_in[2];
  const float* Wr1  = (const float*)d_in[3];
  const float* att1 = (const float*)d_in[4];
  const float* b1   = (const float*)d_in[5];
  const float* Wl2  = (const float*)d_in[6];
  const float* Wr2  = (const float*)d_in[7];
  const float* att2 = (const float*)d_in[8];
  const float* b2   = (const float*)d_in[9];

  const int N = in_sizes[0] / 128;
  const int E = in_sizes[1] / 2;
  const int Etot = E + N;
  float* out = (float*)d_out;
  (void)out_size; (void)n_in; (void)ws_size;

  // ---------------- workspace layout ----------------
  char* ws = (char*)d_ws;
  size_t off_b = 0;
  auto alloc = [&](size_t bytes) {
    void* p = ws + off_b;
    off_b += (bytes + 255) & ~(size_t)255;
    return p;
  };
  const int nblk = (N + 255) / 256;
  unsigned*       xl1p   = (unsigned*)alloc((size_t)N * 64 * 4);  // packed bf16 pairs
  unsigned*       xr1p   = (unsigned*)alloc((size_t)N * 64 * 4);
  float*          h1     = (float*)alloc((size_t)N * 128 * 4);
  int*            bucket = (int*)alloc((size_t)(Etot + 8) * 4);
  int*            esrc   = (int*)alloc((size_t)Etot * 4);
  int*            edst   = (int*)alloc((size_t)Etot * 4);
  int*            csroff = (int*)alloc((size_t)(N + 1) * 4);
  int*            cursor = (int*)alloc((size_t)N * 4);
  int*            count  = (int*)alloc((size_t)N * 4);
  int*            perm   = (int*)alloc((size_t)N * 4);
  int*            bsum   = (int*)alloc(256 * 4);
  int*            hist2d = (int*)alloc((size_t)256 * nblk * 4);
  int*            base2d = (int*)alloc((size_t)256 * nblk * 4);
  int*            gbsum  = (int*)alloc(512 * 4);
  int*            flag   = (int*)alloc(256);
  unsigned short* WbT1   = (unsigned short*)alloc(256 * 128 * 2);
  unsigned short* WbT2   = (unsigned short*)alloc(64 * 128 * 2);

  // layer-2 packed transforms overlay the (then-dead) xl1p region
  unsigned* xl2p = xl1p;
  unsigned* xr2p = xl1p + (size_t)N * 16;

  const int nscan = (N + 255) / 256;
  const int rsz = (N + 7) / 8;
  const int nch = 256;
  const int ce = (Etot + nch - 1) / nch;
  const int T = 256 * nblk;
  const int eblk = (Etot + 255) / 256;

  // ---------------- weight packing (single launch) ----------------
  hipLaunchKernelGGL(packW2_k, dim3((320 * 128 + 255) / 256), dim3(256), 0, stream,
                     Wl1, Wr1, Wl2, Wr2, WbT1, WbT2);

  // ---------------- edge conversion + CSR build (XCD-partitioned) ----------------
  hipLaunchKernelGGL(detect_idx64, dim3(1), dim3(64), 0, stream, ei, N, flag);
  hipLaunchKernelGGL(convert_k, dim3(eblk), dim3(256), 0, stream, ei, flag, esrc, edst, E, Etot);
  hipMemsetAsync(count, 0, (size_t)N * 4, stream);
  hipLaunchKernelGGL(hist_xcd_k, dim3(8 * nch), dim3(256), 0, stream,
                     edst, count, Etot, rsz, N, ce);
  hipLaunchKernelGGL(scan1_k, dim3(nscan), dim3(256), 0, stream, count, bsum, N);
  hipLaunchKernelGGL(scan2_k, dim3(1), dim3(256), 0, stream, bsum, nscan);
  hipLaunchKernelGGL(scan3_k, dim3(nscan), dim3(256), 0, stream, count, bsum, csroff, cursor, N, Etot);
  hipLaunchKernelGGL(scatter_xcd_k, dim3(8 * nch), dim3(256), 0, stream,
                     esrc, edst, cursor, bucket, Etot, rsz, N, ce);

  // ---------------- descending-degree permutation (LPT) ----------------
  hipLaunchKernelGGL(deg_hist2_k, dim3(nblk), dim3(256), 0, stream, csroff, hist2d, N, nblk);
  hipLaunchKernelGGL(gscan_sum_k, dim3((T + 511) / 512), dim3(256), 0, stream, hist2d, gbsum, T);
  hipLaunchKernelGGL(gscan_top_k, dim3(1), dim3(512), 0, stream, gbsum, (T + 511) / 512);
  hipLaunchKernelGGL(gscan_fin_k, dim3((T + 511) / 512), dim3(512), 0, stream, hist2d, gbsum, base2d, T);
  hipLaunchKernelGGL(deg_scatter2_k, dim3(nblk), dim3(256), 0, stream, csroff, base2d, perm, N, nblk);

  // ---------------- layer 1 (pair-interleaved packed layout) ----------------
  hipLaunchKernelGGL((mfma_dual_gemm<256, 128, 64, true>), dim3((N + 63) / 64), dim3(256), 0, stream,
                     x, WbT1, xl1p, xr1p, N);
  hipLaunchKernelGGL(fused_layer1_k, dim3((N + 15) / 16), dim3(256), 0, stream,
                     xl1p, xr1p, csroff, bucket, perm, att1, b1, h1, N);

  // ---------------- layer 2 ----------------
  hipLaunchKernelGGL((mfma_dual_gemm<64, 32, 32, false>), dim3((N + 63) / 64), dim3(256), 0, stream,
                     h1, WbT2, xl2p, xr2p, N);
  hipLaunchKernelGGL(fused_layer2_k, dim3((N + 15) / 16), dim3(256), 0, stream,
                     xl2p, xr2p, csroff, bucket, perm, att2, b2, out, N);
}

// Round 15
// 216.603 us; speedup vs baseline: 2.3066x; 1.0313x over previous
//
#include <hip/hip_runtime.h>

#define NEG 0.2f

typedef __attribute__((ext_vector_type(4))) float f32x4;
typedef __attribute__((ext_vector_type(8))) short bf16x8;

// ---------- bf16 pack/unpack (RNE) ----------
__device__ __forceinline__ float blo(unsigned u) { return __uint_as_float(u << 16); }
__device__ __forceinline__ float bhi(unsigned u) { return __uint_as_float(u & 0xffff0000u); }
__device__ __forceinline__ unsigned bpack(float a, float b) {
  unsigned ua = __float_as_uint(a), ub = __float_as_uint(b);
  unsigned ra = (ua + 0x7fffu + ((ua >> 16) & 1u)) >> 16;
  unsigned rb = (ub + 0x7fffu + ((ub >> 16) & 1u)) >> 16;
  return ra | (rb << 16);
}
__device__ __forceinline__ unsigned short b16(float a) {
  unsigned ua = __float_as_uint(a);
  return (unsigned short)((ua + 0x7fffu + ((ua >> 16) & 1u)) >> 16);
}

// 16-lane xor-butterfly reduce via ds_swizzle (pattern immediate, 3 inst/stage).
__device__ __forceinline__ float red16(float t) {
  t += __int_as_float(__builtin_amdgcn_ds_swizzle(__float_as_int(t), 0x041F));  // xor 1
  t += __int_as_float(__builtin_amdgcn_ds_swizzle(__float_as_int(t), 0x081F));  // xor 2
  t += __int_as_float(__builtin_amdgcn_ds_swizzle(__float_as_int(t), 0x101F));  // xor 4
  t += __int_as_float(__builtin_amdgcn_ds_swizzle(__float_as_int(t), 0x201F));  // xor 8
  return t;
}

// ---------- convert to compact int32 + inline idx-width detection + count zeroing ----------
__global__ void convert_k(const void* __restrict__ ei,
                          int* __restrict__ esrc, int* __restrict__ edst,
                          int* __restrict__ count, int E, int Etot, int N, int n_nodes) {
  __shared__ int is64s;
  if (threadIdx.x < 64) {   // wave 0: detect int64 vs int32 (P(false+) ~ (1/N)^64)
    const long long* e64 = (const long long*)ei;
    long long v = e64[threadIdx.x];
    bool ok = (v >= 0 && v < (long long)n_nodes);
    unsigned long long bm = __ballot(ok);
    if (threadIdx.x == 0) is64s = (bm == ~0ull) ? 1 : 0;
  }
  __syncthreads();
  int is64 = is64s;
  int e = blockIdx.x * 256 + threadIdx.x;
  if (e < N) count[e] = 0;   // fold count-memset into this grid (Etot > N)
  if (e >= Etot) return;
  int src, dst;
  if (e >= E) { src = e - E; dst = e - E; }  // self-loops appended
  else if (is64) {
    const long long* p = (const long long*)ei;
    src = (int)p[e];
    dst = (int)p[(size_t)E + e];
  } else {
    const int* p = (const int*)ei;
    src = p[e];
    dst = p[E + e];
  }
  esrc[e] = src;
  edst[e] = dst;
}

// ---------- XCD-range-partitioned CSR build (compact int32 input) ----------
__global__ void hist_xcd_k(const int* __restrict__ edst, int* __restrict__ count,
                           int Etot, int rsz, int N, int ce) {
  int r = blockIdx.x & 7, c = blockIdx.x >> 3;
  int lo = r * rsz, hi = min(N, lo + rsz);
  int eend = min(Etot, (c + 1) * ce);
  for (int e = c * ce + threadIdx.x; e < eend; e += 256) {
    int dst = edst[e];
    if (dst >= lo && dst < hi) atomicAdd(&count[dst], 1);
  }
}

__global__ void scatter_xcd_k(const int* __restrict__ esrc, const int* __restrict__ edst,
                              int* __restrict__ cursor, int* __restrict__ bucket,
                              int Etot, int rsz, int N, int ce) {
  int r = blockIdx.x & 7, c = blockIdx.x >> 3;
  int lo = r * rsz, hi = min(N, lo + rsz);
  int eend = min(Etot, (c + 1) * ce);
  for (int e = c * ce + threadIdx.x; e < eend; e += 256) {
    int dst = edst[e];
    if (dst >= lo && dst < hi) {
      int pos = atomicAdd(&cursor[dst], 1);
      bucket[pos] = esrc[e];
    }
  }
}

__global__ void scan1_k(const int* __restrict__ count, int* __restrict__ bsum, int n) {
  __shared__ int sd[256];
  int i = blockIdx.x * 256 + threadIdx.x;
  sd[threadIdx.x] = (i < n) ? count[i] : 0;
  __syncthreads();
  for (int o = 128; o; o >>= 1) {
    if (threadIdx.x < o) sd[threadIdx.x] += sd[threadIdx.x + o];
    __syncthreads();
  }
  if (threadIdx.x == 0) bsum[blockIdx.x] = sd[0];
}

__global__ void scan2_k(int* __restrict__ bsum, int nb) {
  __shared__ int sd[256];
  int v = (threadIdx.x < nb) ? bsum[threadIdx.x] : 0;
  sd[threadIdx.x] = v;
  __syncthreads();
  for (int o = 1; o < 256; o <<= 1) {
    int t = (threadIdx.x >= o) ? sd[threadIdx.x - o] : 0;
    __syncthreads();
    sd[threadIdx.x] += t;
    __syncthreads();
  }
  if (threadIdx.x < nb) bsum[threadIdx.x] = sd[threadIdx.x] - v;
}

__global__ void scan3_k(const int* __restrict__ count, const int* __restrict__ bsum,
                        int* __restrict__ off, int* __restrict__ cursor, int n, int etot) {
  __shared__ int sd[256];
  int i = blockIdx.x * 256 + threadIdx.x;
  int v = (i < n) ? count[i] : 0;
  sd[threadIdx.x] = v;
  __syncthreads();
  for (int o = 1; o < 256; o <<= 1) {
    int t = (threadIdx.x >= o) ? sd[threadIdx.x - o] : 0;
    __syncthreads();
    sd[threadIdx.x] += t;
    __syncthreads();
  }
  if (i < n) {
    int ex = bsum[blockIdx.x] + sd[threadIdx.x] - v;
    off[i] = ex;
    cursor[i] = ex;
  }
  if (i == 0) off[n] = etot;
}

// ---------- descending-degree (LPT) permutation: 32-chunk, no global atomics ----------
__global__ void deg_hist3_k(const int* __restrict__ off, int* __restrict__ hist2d,
                            int N, int cs) {   // grid 32 x 256
  __shared__ int h[256];
  h[threadIdx.x] = 0;
  __syncthreads();
  int hi = min(N, (int)(blockIdx.x + 1) * cs);
  for (int i = blockIdx.x * cs + threadIdx.x; i < hi; i += 256) {
    int d = off[i + 1] - off[i];
    d = d < 255 ? d : 255;
    atomicAdd(&h[255 - d], 1);   // LDS atomic; bin 0 = highest degree
  }
  __syncthreads();
  hist2d[threadIdx.x * 32 + blockIdx.x] = h[threadIdx.x];
}

__global__ void deg_scan1_k(const int* __restrict__ in, int* __restrict__ out) {
  // single block, 1024 threads, exactly T = 8192 elements
  __shared__ int sums[1024];
  int t = threadIdx.x;
  int v[8], s = 0;
#pragma unroll
  for (int k = 0; k < 8; ++k) { v[k] = in[t * 8 + k]; s += v[k]; }
  sums[t] = s;
  __syncthreads();
  for (int o = 1; o < 1024; o <<= 1) {
    int x = (t >= o) ? sums[t - o] : 0;
    __syncthreads();
    sums[t] += x;
    __syncthreads();
  }
  int run = sums[t] - s;   // exclusive base of this thread's chunk
#pragma unroll
  for (int k = 0; k < 8; ++k) { out[t * 8 + k] = run; run += v[k]; }
}

__global__ void deg_scatter3_k(const int* __restrict__ off, const int* __restrict__ base2d,
                               int* __restrict__ perm, int N, int cs) {  // grid 32 x 256
  __shared__ int cur[256];
  cur[threadIdx.x] = 0;
  __syncthreads();
  int hi = min(N, (int)(blockIdx.x + 1) * cs);
  for (int i = blockIdx.x * cs + threadIdx.x; i < hi; i += 256) {
    int d = off[i + 1] - off[i];
    d = d < 255 ? d : 255;
    int db = 255 - d;
    int r = atomicAdd(&cur[db], 1);   // LDS atomic (intra-bin order arbitrary; outputs unaffected)
    perm[base2d[db * 32 + blockIdx.x] + r] = i;
  }
}

// ---------- pack weights: [Wl1|Wr1] and [Wl2|Wr2] -> bf16 B^T, one kernel ----------
__global__ void packW2_k(const float* __restrict__ Wl1, const float* __restrict__ Wr1,
                         const float* __restrict__ Wl2, const float* __restrict__ Wr2,
                         unsigned short* __restrict__ WbT1, unsigned short* __restrict__ WbT2) {
  int i = blockIdx.x * 256 + threadIdx.x;   // over 320*128
  if (i >= 320 * 128) return;
  int col = i >> 7, k = i & 127;
  if (col < 256) {
    float v = (col < 128) ? Wl1[(size_t)k * 128 + col] : Wr1[(size_t)k * 128 + (col - 128)];
    WbT1[i] = b16(v);
  } else {
    int c2 = col - 256;   // 0..63
    float v = (c2 < 32) ? Wl2[(size_t)k * 32 + c2] : Wr2[(size_t)k * 32 + (c2 - 32)];
    WbT2[(size_t)c2 * 128 + k] = b16(v);
  }
}

// ---------- MFMA dual GEMM: [xl|xr] = X @ WbT(bf16), K=128; A fp32 or bf16 ----------
template <int NCOL, int C, int HS, bool PAIRI, bool ABF16>
__global__ void mfma_dual_gemm(const void* __restrict__ Xv, const unsigned short* __restrict__ WbT,
                               unsigned* __restrict__ xl_p, unsigned* __restrict__ xr_p, int nrows) {
  constexpr int NF = NCOL / 16;
  constexpr int NPM = C / 2;
  constexpr int FPM = C / 16;
  constexpr int FPH = HS / 16;
  constexpr int POFF = HS / 32;
  const int wave = threadIdx.x >> 6;
  const int lane = threadIdx.x & 63;
  const int row0 = blockIdx.x * 64 + wave * 16;
  const int rA = row0 + (lane & 15);
  const int rAc = (rA < nrows) ? rA : (nrows - 1);
  const int kA = (lane >> 4) * 8;
  const int colB = lane & 15;

  f32x4 acc[NF];
#pragma unroll
  for (int f = 0; f < NF; ++f) acc[f] = (f32x4){0.f, 0.f, 0.f, 0.f};

#pragma unroll
  for (int k0 = 0; k0 < 128; k0 += 32) {
    union { unsigned u[4]; uint4 u4; bf16x8 v; } af;
    if (ABF16) {
      const unsigned short* Xb = (const unsigned short*)Xv;
      af.u4 = *(const uint4*)&Xb[(size_t)rAc * 128 + k0 + kA];
    } else {
      const float* X = (const float*)Xv;
      const float* ax = &X[(size_t)rAc * 128 + k0 + kA];
      float4 a0 = *(const float4*)ax;
      float4 a1 = *(const float4*)(ax + 4);
      af.u[0] = bpack(a0.x, a0.y);
      af.u[1] = bpack(a0.z, a0.w);
      af.u[2] = bpack(a1.x, a1.y);
      af.u[3] = bpack(a1.z, a1.w);
    }
#pragma unroll
    for (int nf = 0; nf < NF; ++nf) {
      union { uint4 u4; bf16x8 v; } bf;
      bf.u4 = *(const uint4*)&WbT[(size_t)(nf * 16 + colB) * 128 + k0 + kA];
      acc[nf] = __builtin_amdgcn_mfma_f32_16x16x32_bf16(af.v, bf.v, acc[nf], 0, 0, 0);
    }
  }

#pragma unroll
  for (int mat = 0; mat < 2; ++mat) {
    unsigned* outp = mat ? xr_p : xl_p;
#pragma unroll
    for (int mf = 0; mf < FPM; ++mf) {
      int head = mf / FPH, hf = mf % FPH;
      if (hf >= POFF) continue;
      int f = mat * FPM + mf;
      int pair = hf * 16 + colB;
      int q = PAIRI ? (2 * pair + head) : (head * (HS / 2) + pair);
#pragma unroll
      for (int r = 0; r < 4; ++r) {
        int row = row0 + ((lane >> 4) << 2) + r;
        if (row < nrows) outp[(size_t)row * NPM + q] = bpack(acc[f][r], acc[f + POFF][r]);
      }
    }
  }
}

// ---------- layer 1 fused: 16 lanes/node, LPT perm, depth-2 pipeline, bf16 h1 out ----------
__global__ void fused_layer1_k(const unsigned* __restrict__ xl_p, const unsigned* __restrict__ xr_p,
                               const int* __restrict__ off, const int* __restrict__ bucket,
                               const int* __restrict__ perm,
                               const float* __restrict__ att, const float* __restrict__ b,
                               unsigned* __restrict__ h1b, int N) {
  int grp = threadIdx.x >> 4, sub = threadIdx.x & 15;
  int idx = blockIdx.x * 16 + grp;
  if (idx >= N) return;
  int node = perm[idx];
  const int c0 = 2 * sub, c1 = 2 * sub + 1;
  uint4 xr4 = *(const uint4*)&xr_p[(size_t)node * 64 + 4 * sub];
  float xr0 = blo(xr4.x), xr1 = bhi(xr4.x);   // h0: ch c0, c0+32
  float xr2 = blo(xr4.y), xr3 = bhi(xr4.y);   // h1: ch 64+c0, 96+c0
  float xr4f = blo(xr4.z), xr5 = bhi(xr4.z);  // h0: ch c1, c1+32
  float xr6 = blo(xr4.w), xr7 = bhi(xr4.w);   // h1: ch 64+c1, 96+c1
  float at0 = att[c0], at1 = att[c0 + 32], at2 = att[64 + c0], at3 = att[96 + c0];
  float at4 = att[c1], at5 = att[c1 + 32], at6 = att[64 + c1], at7 = att[96 + c1];

  float m0 = -INFINITY, m1 = -INFINITY, s0 = 0.f, s1 = 0.f;
  float o0 = 0.f, o1 = 0.f, o2 = 0.f, o3 = 0.f, o4 = 0.f, o5 = 0.f, o6 = 0.f, o7 = 0.f;
  int j = off[node], jend = off[node + 1];

  auto tpart = [&](uint4 v, float* vv, float& t0, float& t1) {
    vv[0] = blo(v.x); vv[1] = bhi(v.x); vv[2] = blo(v.y); vv[3] = bhi(v.y);
    vv[4] = blo(v.z); vv[5] = bhi(v.z); vv[6] = blo(v.w); vv[7] = bhi(v.w);
    float e0 = vv[0] + xr0;  e0 = fmaxf(e0, NEG * e0);
    float e1 = vv[1] + xr1;  e1 = fmaxf(e1, NEG * e1);
    float e2 = vv[2] + xr2;  e2 = fmaxf(e2, NEG * e2);
    float e3 = vv[3] + xr3;  e3 = fmaxf(e3, NEG * e3);
    float e4 = vv[4] + xr4f; e4 = fmaxf(e4, NEG * e4);
    float e5 = vv[5] + xr5;  e5 = fmaxf(e5, NEG * e5);
    float e6 = vv[6] + xr6;  e6 = fmaxf(e6, NEG * e6);
    float e7 = vv[7] + xr7;  e7 = fmaxf(e7, NEG * e7);
    t0 = fmaf(e0, at0, e1 * at1) + fmaf(e4, at4, e5 * at5);
    t1 = fmaf(e2, at2, e3 * at3) + fmaf(e6, at6, e7 * at7);
  };

  auto LD = [&](int jj, uint4& a, uint4& bq, int& cnt) {
    int i0 = bucket[jj];
    bool two = (jj + 1 < jend);
    int i1 = two ? bucket[jj + 1] : i0;
    a  = *(const uint4*)&xl_p[(size_t)i0 * 64 + 4 * sub];
    bq = *(const uint4*)&xl_p[(size_t)i1 * 64 + 4 * sub];
    cnt = two ? 2 : 1;
  };

  uint4 p0a, p0b, p1a, p1b;
  int cnt0 = 0, cnt1 = 0;
  LD(j, p0a, p0b, cnt0);
  bool have1 = (j + 2 < jend);
  if (have1) LD(j + 2, p1a, p1b, cnt1);

  for (;;) {
    bool have2 = (j + 4 < jend);
    uint4 qa, qb;
    int cntq = 0;
    if (have2) LD(j + 4, qa, qb, cntq);   // depth-2 prefetch

    float va[8], vb[8], t0a, t1a, t0b, t1b;
    tpart(p0a, va, t0a, t1a);
    tpart(p0b, vb, t0b, t1b);
    if (cnt0 < 2) { t0b = -1e30f; t1b = -1e30f; }

    t0a = red16(t0a); t1a = red16(t1a);
    t0b = red16(t0b); t1b = red16(t1b);

    float tm0 = fmaxf(t0a, t0b), tm1 = fmaxf(t1a, t1b);
    if (__any((tm0 > m0 + 8.f) || (tm1 > m1 + 8.f))) {
      float nm0 = fmaxf(m0, tm0), nm1 = fmaxf(m1, tm1);
      float c0r = __expf(m0 - nm0), c1r = __expf(m1 - nm1);
      s0 *= c0r; s1 *= c1r;
      o0 *= c0r; o1 *= c0r; o4 *= c0r; o5 *= c0r;
      o2 *= c1r; o3 *= c1r; o6 *= c1r; o7 *= c1r;
      m0 = nm0; m1 = nm1;
    }
    float p0a_e = __expf(t0a - m0), p1a_e = __expf(t1a - m1);
    float p0b_e = __expf(t0b - m0), p1b_e = __expf(t1b - m1);
    s0 += p0a_e + p0b_e;
    s1 += p1a_e + p1b_e;
    o0 = fmaf(p0a_e, va[0], fmaf(p0b_e, vb[0], o0));
    o1 = fmaf(p0a_e, va[1], fmaf(p0b_e, vb[1], o1));
    o4 = fmaf(p0a_e, va[4], fmaf(p0b_e, vb[4], o4));
    o5 = fmaf(p0a_e, va[5], fmaf(p0b_e, vb[5], o5));
    o2 = fmaf(p1a_e, va[2], fmaf(p1b_e, vb[2], o2));
    o3 = fmaf(p1a_e, va[3], fmaf(p1b_e, vb[3], o3));
    o6 = fmaf(p1a_e, va[6], fmaf(p1b_e, vb[6], o6));
    o7 = fmaf(p1a_e, va[7], fmaf(p1b_e, vb[7], o7));

    if (!have1) break;
    p0a = p1a; p0b = p1b; cnt0 = cnt1;
    if (have2) { p1a = qa; p1b = qb; cnt1 = cntq; }
    have1 = have2;
    j += 2;
  }

  float i0 = 1.f / s0, i1 = 1.f / s1;
  auto elu = [](float r) { return r > 0.f ? r : __expf(r) - 1.f; };
  // h1 row in plain bf16 channel order: u32 q holds channels (2q, 2q+1)
  unsigned* row = h1b + (size_t)node * 64;
  float ra, rb;
  ra = elu(fmaf(o0, i0, b[c0]));       rb = elu(fmaf(o4, i0, b[c1]));
  row[sub] = bpack(ra, rb);
  ra = elu(fmaf(o1, i0, b[c0 + 32]));  rb = elu(fmaf(o5, i0, b[c1 + 32]));
  row[16 + sub] = bpack(ra, rb);
  ra = elu(fmaf(o2, i1, b[64 + c0]));  rb = elu(fmaf(o6, i1, b[64 + c1]));
  row[32 + sub] = bpack(ra, rb);
  ra = elu(fmaf(o3, i1, b[96 + c0]));  rb = elu(fmaf(o7, i1, b[96 + c1]));
  row[48 + sub] = bpack(ra, rb);
}

// ---------- layer 2 fused: 16 lanes per node, LPT perm ----------
__global__ void fused_layer2_k(const unsigned* __restrict__ xl_p, const unsigned* __restrict__ xr_p,
                               const int* __restrict__ off, const int* __restrict__ bucket,
                               const int* __restrict__ perm,
                               const float* __restrict__ att, const float* __restrict__ b,
                               float* __restrict__ out, int N) {
  int idx = blockIdx.x * 16 + (threadIdx.x >> 4);
  int lane = threadIdx.x & 15;
  if (idx >= N) return;
  int node = perm[idx];
  unsigned xru = xr_p[(size_t)node * 16 + lane];
  float xr_a = blo(xru), xr_b = bhi(xru);
  float att_a = att[lane], att_b = att[lane + 16];
  float m = -INFINITY, s = 0.f, oa = 0.f, ob = 0.f;
  int j0 = off[node], jend = off[node + 1];

  auto tpart = [&](unsigned vu, float& va, float& vb) {
    va = blo(vu); vb = bhi(vu);
    float ea = va + xr_a; ea = fmaxf(ea, NEG * ea);
    float eb = vb + xr_b; eb = fmaxf(eb, NEG * eb);
    return fmaf(ea, att_a, eb * att_b);
  };

  auto upd4 = [&](const unsigned* v, int nvalid) {
    float va0, vb0, va1, vb1, va2, vb2, va3, vb3;
    float t0 = tpart(v[0], va0, vb0);
    float t1 = tpart(v[1], va1, vb1);
    float t2 = tpart(v[2], va2, vb2);
    float t3 = tpart(v[3], va3, vb3);
    if (nvalid < 4) {
      if (nvalid <= 1) t1 = -1e30f;
      if (nvalid <= 2) t2 = -1e30f;
      t3 = -1e30f;
    }
    t0 = red16(t0); t1 = red16(t1); t2 = red16(t2); t3 = red16(t3);
    float tm = fmaxf(fmaxf(t0, t1), fmaxf(t2, t3));
    if (__any(tm > m + 8.f)) {
      float nm = fmaxf(m, tm);
      float c = __expf(m - nm);
      s *= c; oa *= c; ob *= c;
      m = nm;
    }
    float p0 = __expf(t0 - m), p1 = __expf(t1 - m);
    float p2 = __expf(t2 - m), p3 = __expf(t3 - m);
    s += (p0 + p1) + (p2 + p3);
    oa = fmaf(p0, va0, fmaf(p1, va1, fmaf(p2, va2, fmaf(p3, va3, oa))));
    ob = fmaf(p0, vb0, fmaf(p1, vb1, fmaf(p2, vb2, fmaf(p3, vb3, ob))));
  };

  unsigned cv[4], nv[4];
  int deg = jend - j0;
#pragma unroll
  for (int k = 0; k < 4; ++k) {
    int idx2 = j0 + ((k < deg) ? k : 0);
    cv[k] = xl_p[(size_t)bucket[idx2] * 16 + lane];
  }
  int j = j0;
  for (;;) {
    int jn = j + 4;
    bool more = jn < jend;
    if (more) {
      int rem = jend - jn;
#pragma unroll
      for (int k = 0; k < 4; ++k) {
        int idx2 = jn + ((k < rem) ? k : 0);
        nv[k] = xl_p[(size_t)bucket[idx2] * 16 + lane];
      }
    }
    int nvalid = jend - j; if (nvalid > 4) nvalid = 4;
    upd4(cv, nvalid);
    if (!more) break;
#pragma unroll
    for (int k = 0; k < 4; ++k) cv[k] = nv[k];
    j = jn;
  }

  float inv = 1.f / s;
  out[(size_t)node * 32 + lane]      = fmaf(oa, inv, b[lane]);
  out[(size_t)node * 32 + 16 + lane] = fmaf(ob, inv, b[lane + 16]);
}

extern "C" void kernel_launch(void* const* d_in, const int* in_sizes, int n_in,
                              void* d_out, int out_size, void* d_ws, size_t ws_size,
                              hipStream_t stream) {
  const float* x    = (const float*)d_in[0];
  const void*  ei   = d_in[1];
  const float* Wl1  = (const float*)d_in[2];
  const float* Wr1  = (const float*)d_in[3];
  const float* att1 = (const float*)d_in[4];
  const float* b1   = (const float*)d_in[5];
  const float* Wl2  = (const float*)d_in[6];
  const float* Wr2  = (const float*)d_in[7];
  const float* att2 = (const float*)d_in[8];
  const float* b2   = (const float*)d_in[9];

  const int N = in_sizes[0] / 128;
  const int E = in_sizes[1] / 2;
  const int Etot = E + N;
  float* out = (float*)d_out;
  (void)out_size; (void)n_in; (void)ws_size;

  // ---------------- workspace layout ----------------
  char* ws = (char*)d_ws;
  size_t off_b = 0;
  auto alloc = [&](size_t bytes) {
    void* p = ws + off_b;
    off_b += (bytes + 255) & ~(size_t)255;
    return p;
  };
  unsigned*       xl1p   = (unsigned*)alloc((size_t)N * 64 * 4);  // packed bf16 pairs
  unsigned*       xr1p   = (unsigned*)alloc((size_t)N * 64 * 4);
  unsigned*       h1b    = (unsigned*)alloc((size_t)N * 64 * 4);  // h1 as bf16 rows
  int*            bucket = (int*)alloc((size_t)(Etot + 8) * 4);
  int*            esrc   = (int*)alloc((size_t)Etot * 4);
  int*            edst   = (int*)alloc((size_t)Etot * 4);
  int*            csroff = (int*)alloc((size_t)(N + 1) * 4);
  int*            cursor = (int*)alloc((size_t)N * 4);
  int*            count  = (int*)alloc((size_t)N * 4);
  int*            perm   = (int*)alloc((size_t)N * 4);
  int*            bsum   = (int*)alloc(256 * 4);
  int*            hist2d = (int*)alloc(256 * 32 * 4);
  int*            base2d = (int*)alloc(256 * 32 * 4);
  unsigned short* WbT1   = (unsigned short*)alloc(256 * 128 * 2);
  unsigned short* WbT2   = (unsigned short*)alloc(64 * 128 * 2);

  // layer-2 packed transforms overlay the (then-dead) xl1p region
  unsigned* xl2p = xl1p;
  unsigned* xr2p = xl1p + (size_t)N * 16;

  const int nscan = (N + 255) / 256;
  const int rsz = (N + 7) / 8;
  const int nch = 256;
  const int ce = (Etot + nch - 1) / nch;
  const int eblk = (Etot + 255) / 256;
  const int cs = (N + 31) / 32;   // nodes per deg chunk

  // 1. weight packing (independent)
  hipLaunchKernelGGL(packW2_k, dim3((320 * 128 + 255) / 256), dim3(256), 0, stream,
                     Wl1, Wr1, Wl2, Wr2, WbT1, WbT2);

  // 2. edge conversion (+ inline detection + count zeroing)
  hipLaunchKernelGGL(convert_k, dim3(eblk), dim3(256), 0, stream,
                     ei, esrc, edst, count, E, Etot, N, N);

  // 3-7. CSR build (XCD-partitioned)
  hipLaunchKernelGGL(hist_xcd_k, dim3(8 * nch), dim3(256), 0, stream,
                     edst, count, Etot, rsz, N, ce);
  hipLaunchKernelGGL(scan1_k, dim3(nscan), dim3(256), 0, stream, count, bsum, N);
  hipLaunchKernelGGL(scan2_k, dim3(1), dim3(256), 0, stream, bsum, nscan);
  hipLaunchKernelGGL(scan3_k, dim3(nscan), dim3(256), 0, stream, count, bsum, csroff, cursor, N, Etot);
  hipLaunchKernelGGL(scatter_xcd_k, dim3(8 * nch), dim3(256), 0, stream,
                     esrc, edst, cursor, bucket, Etot, rsz, N, ce);

  // 8-10. descending-degree permutation (LPT), 3 dispatches
  hipLaunchKernelGGL(deg_hist3_k, dim3(32), dim3(256), 0, stream, csroff, hist2d, N, cs);
  hipLaunchKernelGGL(deg_scan1_k, dim3(1), dim3(1024), 0, stream, hist2d, base2d);
  hipLaunchKernelGGL(deg_scatter3_k, dim3(32), dim3(256), 0, stream, csroff, base2d, perm, N, cs);

  // 11-12. layer 1
  hipLaunchKernelGGL((mfma_dual_gemm<256, 128, 64, true, false>), dim3((N + 63) / 64), dim3(256), 0,
                     stream, (const void*)x, WbT1, xl1p, xr1p, N);
  hipLaunchKernelGGL(fused_layer1_k, dim3((N + 15) / 16), dim3(256), 0, stream,
                     xl1p, xr1p, csroff, bucket, perm, att1, b1, h1b, N);

  // 13-14. layer 2 (GEMM reads bf16 h1 directly)
  hipLaunchKernelGGL((mfma_dual_gemm<64, 32, 32, false, true>), dim3((N + 63) / 64), dim3(256), 0,
                     stream, (const void*)h1b, WbT2, xl2p, xr2p, N);
  hipLaunchKernelGGL(fused_layer2_k, dim3((N + 15) / 16), dim3(256), 0, stream,
                     xl2p, xr2p, csroff, bucket, perm, att2, b2, out, N);
}